// Round 15
// baseline (318.101 us; speedup 1.0000x reference)
//
#include <hip/hip_runtime.h>

#define BATCH   32
#define SEQ     2048
#define IN_DIM  32
#define HID     512
#define STATE   64
#define NLAYERS 4
#define NTOK    (BATCH*SEQ)          // 65536
#define EPS     1e-5f
#define KTAN    2.8853900817779268f  // 2*log2(e)
#define NCHUNK  32                   // scan chunks per batch
#define WARMUP  32                   // contraction warmup steps

#define CF4(p) (*reinterpret_cast<const float4*>(p))

typedef __attribute__((ext_vector_type(8))) short short8v;
typedef __attribute__((ext_vector_type(4))) float f32x4;

__device__ __forceinline__ float fast_exp2(float x){ return __builtin_amdgcn_exp2f(x); }
__device__ __forceinline__ float fast_rcp(float x){ return __builtin_amdgcn_rcpf(x); }
__device__ __forceinline__ short f2bf(float f){           // RNE float->bf16
  unsigned u = __float_as_uint(f);
  unsigned r = (u + 0x7FFF + ((u>>16)&1)) >> 16;
  return (short)r;
}
__device__ __forceinline__ float bf2f(short s){
  return __uint_as_float(((unsigned)(unsigned short)s) << 16);
}

// ---------------------------------------------------------------------------
// All precompute, 38 blocks x 256 threads.
__global__ __launch_bounds__(256) void k_prep(
    const float* __restrict__ A, const float* __restrict__ g,
    const float* __restrict__ b, const float* __restrict__ Win,
    const float* __restrict__ bin, const float* __restrict__ C,
    short* __restrict__ ApT, float* __restrict__ GA, float* __restrict__ BA,
    short* __restrict__ WA1Th, short* __restrict__ WA1Tl,
    float* __restrict__ binA, short* __restrict__ Cb, short* __restrict__ WinT)
{
  __shared__ float red[4][64], red2[4][64];
  int tid = threadIdx.x;
  int s = tid & 63, part = tid >> 6;
  int blk = blockIdx.x;
  if (blk < NLAYERS){
    int l = blk;
    const float* Al = A + l*HID*STATE;
    const float* Cl = C + l*HID*STATE;
    const float* gl = g + l*HID;
    const float* bl = b + l*HID;
    float ga=0.f, ba=0.f;
    for (int j=part*128; j<(part+1)*128; ++j){
      float a  = Al[j*STATE+s];
      float ap = gl[j]*a;
      ApT[l*HID*STATE + s*HID + j] = f2bf(ap);
      Cb[l*HID*STATE + j*STATE + s] = f2bf(Cl[j*STATE+s]);
      ga += ap; ba = fmaf(bl[j], a, ba);
    }
    red[part][s]=ga; red2[part][s]=ba;
    __syncthreads();
    if (tid < 64){
      GA[l*STATE+s] = red[0][s]+red[1][s]+red[2][s]+red[3][s];
      BA[l*STATE+s] = red2[0][s]+red2[1][s]+red2[2][s]+red2[3][s];
    }
  } else if (blk < NLAYERS+32){
    int k = blk - NLAYERS;
    const float* w = Win + k*HID;
    float acc = 0.f;
    for (int j=part*128; j<(part+1)*128; ++j)
      acc = fmaf(w[j], g[j]*A[j*STATE+s], acc);
    red[part][s] = acc;
    __syncthreads();
    if (tid < 64){
      float v = red[0][s]+red[1][s]+red[2][s]+red[3][s];
      short hi = f2bf(v);
      WA1Th[s*IN_DIM + k] = hi;
      WA1Tl[s*IN_DIM + k] = f2bf(v - bf2f(hi));
    }
  } else if (blk == NLAYERS+32){
    float acc = 0.f;
    for (int j=part*128; j<(part+1)*128; ++j)
      acc = fmaf(bin[j], g[j]*A[j*STATE+s], acc);
    red[part][s] = acc;
    __syncthreads();
    if (tid < 64) binA[s] = red[0][s]+red[1][s]+red[2][s]+red[3][s];
  } else {
    for (int e = tid; e < HID*IN_DIM; e += 256){
      int cc = e >> 5, k = e & 31;
      WinT[cc*IN_DIM + k] = f2bf(Win[k*HID + cc]);
    }
  }
}

// ---------------------------------------------------------------------------
// Fused input via MFMA: h(bf16)=x@Win+bin (vectorized stores via Ysh),
// stats0, U0 (3-term bf16-split, fp16 out). BM=64, grid 1024.
__global__ __launch_bounds__(256) void k_input(const float* __restrict__ x,
    const short* __restrict__ WinT, const float* __restrict__ bin,
    const short* __restrict__ WA1Th, const short* __restrict__ WA1Tl,
    const float* __restrict__ binA,
    const float* __restrict__ GA0, const float* __restrict__ BA0,
    short* __restrict__ h, _Float16* __restrict__ U, float2* __restrict__ stats)
{
  __shared__ __align__(16) short xhi[64][72];
  __shared__ __align__(16) short xlo[64][72];
  __shared__ __align__(16) short Ysh[64][76];
  __shared__ float2 statS[64];
  int m0 = blockIdx.x * 64;
  int tid = threadIdx.x;
  int w = tid >> 6, lane = tid & 63;
  int c = lane & 15, q = lane >> 4;
  int vrow = tid >> 3, vcb = tid & 7;   // vector phase: 32 rows x 8 colblocks
  #pragma unroll
  for (int i=0;i<8;i++){
    int idx = tid + i*256;
    int row = idx >> 5, k = idx & 31;
    float v = x[(size_t)(m0+row)*IN_DIM + k];
    short hi = f2bf(v);
    xhi[row][k] = hi;
    xlo[row][k] = f2bf(v - bf2f(hi));
  }
  __syncthreads();
  short8v ah = *reinterpret_cast<const short8v*>(&xhi[w*16 + c][q*8]);
  short8v al = *reinterpret_cast<const short8v*>(&xlo[w*16 + c][q*8]);
  float sum0=0.f, sq0=0.f, sum1=0.f, sq1=0.f;
  for (int jc=0; jc<HID; jc+=64){
    #pragma unroll
    for (int t=0;t<4;t++){
      short8v bv = *reinterpret_cast<const short8v*>(&WinT[(size_t)(jc + t*16 + c)*IN_DIM + q*8]);
      f32x4 a = {0.f,0.f,0.f,0.f};
      a = __builtin_amdgcn_mfma_f32_16x16x32_bf16(ah, bv, a, 0, 0, 0);
      int col = jc + t*16 + c;
      float bj = bin[col];
      #pragma unroll
      for (int r=0;r<4;r++)
        Ysh[w*16 + q*4 + r][t*16 + c] = f2bf(a[r] + bj);
    }
    __syncthreads();
    #pragma unroll
    for (int rep=0; rep<2; ++rep){
      int row = vrow + rep*32;
      int m = m0 + row;
      short8v yv = *reinterpret_cast<const short8v*>(&Ysh[row][vcb*8]);
      *reinterpret_cast<short8v*>(&h[(size_t)m*HID + jc + vcb*8]) = yv;
      float lsum=0.f, lsq=0.f;
      #pragma unroll
      for (int i=0;i<8;i++){
        float o = bf2f(yv[i]);
        lsum += o; lsq += o*o;
      }
      if (rep) { sum1 += lsum; sq1 += lsq; } else { sum0 += lsum; sq0 += lsq; }
    }
    __syncthreads();
  }
  #pragma unroll
  for (int off=1; off<8; off<<=1){
    sum0 += __shfl_xor(sum0, off);  sq0 += __shfl_xor(sq0, off);
    sum1 += __shfl_xor(sum1, off);  sq1 += __shfl_xor(sq1, off);
  }
  if (vcb == 0){
    float m0v = sum0*(1.f/HID);
    float v0 = sq0*(1.f/HID) - m0v*m0v;
    float2 s0 = make_float2(m0v, rsqrtf(fmaxf(v0,0.f)+EPS));
    stats[m0 + vrow] = s0;  statS[vrow] = s0;
    float m1v = sum1*(1.f/HID);
    float v1 = sq1*(1.f/HID) - m1v*m1v;
    float2 s1 = make_float2(m1v, rsqrtf(fmaxf(v1,0.f)+EPS));
    stats[m0 + 32 + vrow] = s1;  statS[32 + vrow] = s1;
  }
  __syncthreads();
  float mu[4], rs[4];
  #pragma unroll
  for (int r=0;r<4;r++){
    float2 s2 = statS[w*16 + q*4 + r];
    mu[r]=s2.x; rs[r]=s2.y;
  }
  #pragma unroll
  for (int t=0;t<4;t++){
    short8v bh  = *reinterpret_cast<const short8v*>(&WA1Th[(size_t)(t*16 + c)*IN_DIM + q*8]);
    short8v blv = *reinterpret_cast<const short8v*>(&WA1Tl[(size_t)(t*16 + c)*IN_DIM + q*8]);
    f32x4 a = {0.f,0.f,0.f,0.f};
    a = __builtin_amdgcn_mfma_f32_16x16x32_bf16(ah, bh, a, 0, 0, 0);
    a = __builtin_amdgcn_mfma_f32_16x16x32_bf16(al, bh, a, 0, 0, 0);
    a = __builtin_amdgcn_mfma_f32_16x16x32_bf16(ah, blv, a, 0, 0, 0);
    int s = t*16 + c;
    float ga = GA0[s], ba = BA0[s], bA = binA[s];
    #pragma unroll
    for (int r=0;r<4;r++){
      int m = m0 + w*16 + q*4 + r;
      float u = a[r] + bA;
      U[(size_t)m*STATE + s] = (_Float16)fmaf(KTAN, rs[r]*(u - mu[r]*ga) + ba, KTAN);
    }
  }
}

// ---------------------------------------------------------------------------
// U = KTAN*( rstd*(h@A' - mu*GA) + BA ) + KTAN via bf16 MFMA (layers 1..3).
// Zero LDS / zero barriers: MFMA fragments load directly from global.
// A-frag: per row, a0+a1 q-lanes cover exactly one 128B line of h.
// B (ApT, 64KB/layer) is L1/L2 resident. BM=64, grid 1024, 4 waves.
__global__ __launch_bounds__(256) void k_ugemm(const short* __restrict__ hb,
    const float2* __restrict__ stats, const short* __restrict__ ApT,
    const float* __restrict__ GA, const float* __restrict__ BA,
    _Float16* __restrict__ U)
{
  int m0 = blockIdx.x * 64;
  int tid = threadIdx.x;
  int w = tid >> 6, lane = tid & 63;
  int c = lane & 15, q = lane >> 4;
  float mu[4], rs[4];
  #pragma unroll
  for (int r=0;r<4;r++){
    float2 s2 = stats[m0 + w*16 + q*4 + r];
    mu[r]=s2.x; rs[r]=s2.y;
  }
  const short* arow = &hb[(size_t)(m0 + w*16 + c)*HID];
  f32x4 acc[4] = {{0.f,0.f,0.f,0.f},{0.f,0.f,0.f,0.f},{0.f,0.f,0.f,0.f},{0.f,0.f,0.f,0.f}};
  #pragma unroll
  for (int kc=0; kc<HID; kc+=64){
    short8v a0 = *reinterpret_cast<const short8v*>(arow + kc + q*8);
    short8v a1 = *reinterpret_cast<const short8v*>(arow + kc + 32 + q*8);
    #pragma unroll
    for (int t=0;t<4;t++){
      short8v b0 = *reinterpret_cast<const short8v*>(&ApT[(size_t)(t*16 + c)*HID + kc + q*8]);
      short8v b1 = *reinterpret_cast<const short8v*>(&ApT[(size_t)(t*16 + c)*HID + kc + 32 + q*8]);
      acc[t] = __builtin_amdgcn_mfma_f32_16x16x32_bf16(a0, b0, acc[t], 0, 0, 0);
      acc[t] = __builtin_amdgcn_mfma_f32_16x16x32_bf16(a1, b1, acc[t], 0, 0, 0);
    }
  }
  #pragma unroll
  for (int t=0;t<4;t++){
    int s = t*16 + c;
    float ga = GA[s], ba = BA[s];
    #pragma unroll
    for (int r=0;r<4;r++){
      int m = m0 + w*16 + q*4 + r;
      U[(size_t)m*STATE + s] = (_Float16)fmaf(KTAN, rs[r]*(acc[t][r] - mu[r]*ga) + ba, KTAN);
    }
  }
}

// ---------------------------------------------------------------------------
// Chunked scan with contraction warmup (R12-verified), U in fp16.
__global__ __launch_bounds__(64) void k_scan(const _Float16* __restrict__ U,
                                             short* __restrict__ H)
{
  int b = blockIdx.x >> 5;
  int p = blockIdx.x & 31;
  int s = threadIdx.x;
  const _Float16* Ub = U + (size_t)b*SEQ*STATE + s;
  short* Hb = H + (size_t)b*SEQ*STATE + s;
  float r = 0.5f;
  float cur[32], nxt[32];
  int t = (p == 0) ? 0 : (p*64 - WARMUP);
  int nsub = (p == 0) ? 2 : 3;
  #pragma unroll
  for (int i=0;i<32;i++) cur[i] = (float)Ub[(t+i)*STATE];
  for (int cidx=0; cidx<nsub; ++cidx){
    bool has_next = (cidx+1 < nsub);
    if (has_next){
      #pragma unroll
      for (int i=0;i<32;i++) nxt[i] = (float)Ub[(t+32+i)*STATE];
    }
    if ((p == 0) || (cidx > 0)){
      #pragma unroll
      for (int i=0;i<32;i++){
        float e = fast_exp2(fmaf(-2.f*KTAN, r, cur[i]));
        r = fast_rcp(1.f + e);
        Hb[(t+i)*STATE] = f2bf(fmaf(-2.f, r, 1.f));
      }
    } else {
      #pragma unroll
      for (int i=0;i<32;i++){
        float e = fast_exp2(fmaf(-2.f*KTAN, r, cur[i]));
        r = fast_rcp(1.f + e);
      }
    }
    if (has_next){
      #pragma unroll
      for (int i=0;i<32;i++) cur[i] = nxt[i];
    }
    t += 32;
  }
}

// ---------------------------------------------------------------------------
// Y epilogue (R12-verified): MFMA -> Ysh(bf16 LDS) -> vectorized short8 h-RMW.
__global__ __launch_bounds__(256) void k_yep4(
    short* __restrict__ h, const short* __restrict__ Hg,
    const short* __restrict__ Cb, const float* __restrict__ Dl,
    const float* __restrict__ gl, const float* __restrict__ bl,
    const float2* __restrict__ stats_in, float2* __restrict__ stats_out)
{
  __shared__ __align__(16) short Hsh[64][72];   // 9.2 KB
  __shared__ __align__(16) short Csh[64][72];   // 9.2 KB
  __shared__ __align__(16) short Ysh[64][76];   // 9.7 KB
  int m0 = blockIdx.x * 64;
  int tid = threadIdx.x;
  int w = tid >> 6, lane = tid & 63;
  int c = lane & 15, q = lane >> 4;
  int vrow = tid >> 3;
  int vcb  = tid & 7;
  #pragma unroll
  for (int p=0;p<2;p++){
    int idx = tid + p*256;
    int row = idx >> 3, kb = idx & 7;
    *reinterpret_cast<short8v*>(&Hsh[row][kb*8]) =
      *reinterpret_cast<const short8v*>(&Hg[(size_t)(m0+row)*STATE + kb*8]);
  }
  float2 sin0 = stats_in[m0 + vrow];
  float2 sin1 = stats_in[m0 + 32 + vrow];
  float sum0=0.f, sq0=0.f, sum1=0.f, sq1=0.f;
  __syncthreads();
  short8v a0 = *reinterpret_cast<const short8v*>(&Hsh[w*16 + c][q*8]);
  short8v a1 = *reinterpret_cast<const short8v*>(&Hsh[w*16 + c][32 + q*8]);
  for (int jc=0; jc<HID; jc+=64){
    #pragma unroll
    for (int p=0;p<2;p++){
      int idx = tid + p*256;
      int col = idx >> 3, kb = idx & 7;
      *reinterpret_cast<short8v*>(&Csh[col][kb*8]) =
        *reinterpret_cast<const short8v*>(&Cb[(size_t)(jc+col)*STATE + kb*8]);
    }
    __syncthreads();
    #pragma unroll
    for (int t=0;t<4;t++){
      short8v b0 = *reinterpret_cast<const short8v*>(&Csh[t*16 + c][q*8]);
      short8v b1 = *reinterpret_cast<const short8v*>(&Csh[t*16 + c][32 + q*8]);
      f32x4 a = {0.f,0.f,0.f,0.f};
      a = __builtin_amdgcn_mfma_f32_16x16x32_bf16(a0, b0, a, 0, 0, 0);
      a = __builtin_amdgcn_mfma_f32_16x16x32_bf16(a1, b1, a, 0, 0, 0);
      #pragma unroll
      for (int r=0;r<4;r++)
        Ysh[w*16 + q*4 + r][t*16 + c] = f2bf(a[r]);
    }
    __syncthreads();
    int col0 = jc + vcb*8;
    float4 gA = CF4(&gl[col0]), gB = CF4(&gl[col0+4]);
    float4 bA = CF4(&bl[col0]), bB = CF4(&bl[col0+4]);
    float4 dA = CF4(&Dl[col0]), dB = CF4(&Dl[col0+4]);
    float ga[8] = {gA.x,gA.y,gA.z,gA.w,gB.x,gB.y,gB.z,gB.w};
    float ba[8] = {bA.x,bA.y,bA.z,bA.w,bB.x,bB.y,bB.z,bB.w};
    float da[8] = {dA.x,dA.y,dA.z,dA.w,dB.x,dB.y,dB.z,dB.w};
    #pragma unroll
    for (int rep=0; rep<2; ++rep){
      int row = vrow + rep*32;
      int m = m0 + row;
      float mu_ = rep ? sin1.x : sin0.x;
      float rs_ = rep ? sin1.y : sin0.y;
      short8v hv = *reinterpret_cast<const short8v*>(&h[(size_t)m*HID + col0]);
      short8v yv = *reinterpret_cast<const short8v*>(&Ysh[row][vcb*8]);
      short8v ov;
      float lsum=0.f, lsq=0.f;
      #pragma unroll
      for (int i=0;i<8;i++){
        float hvf = bf2f(hv[i]);
        float o = hvf + bf2f(yv[i]) + fmaf((hvf-mu_)*rs_, ga[i], ba[i])*da[i];
        ov[i] = f2bf(o);
        lsum += o; lsq += o*o;
      }
      *reinterpret_cast<short8v*>(&h[(size_t)m*HID + col0]) = ov;
      if (rep) { sum1 += lsum; sq1 += lsq; } else { sum0 += lsum; sq0 += lsq; }
    }
  }
  #pragma unroll
  for (int off=1; off<8; off<<=1){
    sum0 += __shfl_xor(sum0, off);  sq0 += __shfl_xor(sq0, off);
    sum1 += __shfl_xor(sum1, off);  sq1 += __shfl_xor(sq1, off);
  }
  if (vcb == 0){
    float m0v = sum0*(1.f/HID);
    float v0 = sq0*(1.f/HID) - m0v*m0v;
    stats_out[m0 + vrow] = make_float2(m0v, rsqrtf(fmaxf(v0,0.f)+EPS));
    float m1v = sum1*(1.f/HID);
    float v1 = sq1*(1.f/HID) - m1v*m1v;
    stats_out[m0 + 32 + vrow] = make_float2(m1v, rsqrtf(fmaxf(v1,0.f)+EPS));
  }
}

// ---------------------------------------------------------------------------
__global__ __launch_bounds__(256) void k_head(const short* __restrict__ h,
   const float2* __restrict__ stats, const float* __restrict__ ng, const float* __restrict__ nb,
   const float* __restrict__ W1, const float* __restrict__ b1,
   const float* __restrict__ W2, const float* __restrict__ b2,
   float* __restrict__ out)
{
  int bb = blockIdx.x;
  int m = bb*SEQ + (SEQ-1);
  int tid = threadIdx.x;
  __shared__ float xs[HID];
  __shared__ float red[8];
  float2 st = stats[m];
  #pragma unroll
  for (int i=0;i<2;i++){
    int j = tid + i*256;
    float v = bf2f(h[(size_t)m*HID + j]);
    xs[j] = fmaf((v - st.x)*st.y, ng[j], nb[j]);
  }
  __syncthreads();
  float acc = b1[tid];
  #pragma unroll 8
  for (int j=0;j<HID;j++) acc = fmaf(xs[j], W1[j*(HID/2) + tid], acc);
  float ge = 0.5f*acc*(1.f + erff(acc*0.70710678118654752f));
  float p0 = ge*W2[tid*2+0];
  float p1 = ge*W2[tid*2+1];
  #pragma unroll
  for (int off=32; off; off>>=1){ p0 += __shfl_down(p0, off); p1 += __shfl_down(p1, off); }
  int wid = tid>>6;
  if ((tid&63)==0){ red[wid*2]=p0; red[wid*2+1]=p1; }
  __syncthreads();
  if (tid==0){
    float o0=b2[0], o1=b2[1];
    #pragma unroll
    for (int w=0;w<4;w++){ o0+=red[w*2]; o1+=red[w*2+1]; }
    out[bb*2+0]=o0; out[bb*2+1]=o1;
  }
}

// ---------------------------------------------------------------------------
extern "C" void kernel_launch(void* const* d_in, const int* in_sizes, int n_in,
                              void* d_out, int out_size, void* d_ws, size_t ws_size,
                              hipStream_t stream)
{
  (void)in_sizes; (void)n_in; (void)out_size; (void)ws_size;
  const float* x   = (const float*)d_in[0];
  const float* Win = (const float*)d_in[1];
  const float* bin = (const float*)d_in[2];
  const float* A   = (const float*)d_in[3];
  const float* C   = (const float*)d_in[4];
  const float* Dv  = (const float*)d_in[5];
  const float* lng = (const float*)d_in[6];
  const float* lnb = (const float*)d_in[7];
  const float* ng  = (const float*)d_in[8];
  const float* nb  = (const float*)d_in[9];
  const float* W1  = (const float*)d_in[10];
  const float* b1  = (const float*)d_in[11];
  const float* W2  = (const float*)d_in[12];
  const float* b2  = (const float*)d_in[13];
  float* out = (float*)d_out;
  char* ws = (char*)d_ws;
  short*     hb   = (short*)(ws + 0);                    //  67,108,864 (bf16)
  _Float16*  Ubuf = (_Float16*)(ws + (size_t)67108864);  //   8,388,608 (fp16)
  short*     Hbuf = (short*)(ws + (size_t)83886080);     //   8,388,608 (bf16)
  float2*    st0  = (float2*)(ws + (size_t)92274688);    //     524,288
  float2*    st1  = (float2*)(ws + (size_t)92798976);    //     524,288
  short*     ApT  = (short*)(ws + (size_t)93323264);     //     262,144 (bf16)
  float*     GAb  = (float*)(ws + (size_t)93585408);     //       1,024
  float*     BAb  = (float*)(ws + (size_t)93586432);     //       1,024
  float*     binAb= (float*)(ws + (size_t)93587456);     //         256
  short*     Cb   = (short*)(ws + (size_t)93587712);     //     262,144 (bf16)
  short*     WinT = (short*)(ws + (size_t)93849856);     //      32,768 (bf16)
  short*     WA1Th= (short*)(ws + (size_t)93882624);     //       4,096 (bf16)
  short*     WA1Tl= (short*)(ws + (size_t)93886720);     //       4,096 (bf16)

  hipLaunchKernelGGL(k_prep,  dim3(38), dim3(256), 0, stream,
      A, lng, lnb, Win, bin, C, ApT, GAb, BAb, WA1Th, WA1Tl, binAb, Cb, WinT);
  hipLaunchKernelGGL(k_input, dim3(NTOK/64), dim3(256), 0, stream,
      x, WinT, bin, WA1Th, WA1Tl, binAb, GAb, BAb, hb, Ubuf, st0);
  float2* scur = st0; float2* snxt = st1;
  for (int l=0; l<NLAYERS; ++l){
    if (l > 0){
      hipLaunchKernelGGL(k_ugemm, dim3(NTOK/64), dim3(256), 0, stream,
          hb, scur, ApT + l*HID*STATE, GAb + l*STATE, BAb + l*STATE, Ubuf);
    }
    hipLaunchKernelGGL(k_scan, dim3(BATCH*NCHUNK), dim3(64), 0, stream, Ubuf, Hbuf);
    hipLaunchKernelGGL(k_yep4, dim3(NTOK/64), dim3(256), 0, stream,
        hb, Hbuf, Cb + l*HID*STATE, Dv + l*HID, lng + l*HID, lnb + l*HID, scur, snxt);
    float2* t = scur; scur = snxt; snxt = t;
  }
  hipLaunchKernelGGL(k_head, dim3(BATCH), dim3(256), 0, stream,
      hb, scur, ng, nb, W1, b1, W2, b2, out);
}

// Round 16
// 307.649 us; speedup vs baseline: 1.0340x; 1.0340x over previous
//
#include <hip/hip_runtime.h>

#define BATCH   32
#define SEQ     2048
#define IN_DIM  32
#define HID     512
#define STATE   64
#define NLAYERS 4
#define NTOK    (BATCH*SEQ)          // 65536
#define EPS     1e-5f
#define KTAN    2.8853900817779268f  // 2*log2(e)
#define NCHUNK  32                   // scan chunks per batch
#define WARMUP  32                   // contraction warmup steps

#define CF4(p) (*reinterpret_cast<const float4*>(p))

typedef __attribute__((ext_vector_type(8))) short short8v;
typedef __attribute__((ext_vector_type(4))) float f32x4;

__device__ __forceinline__ float fast_exp2(float x){ return __builtin_amdgcn_exp2f(x); }
__device__ __forceinline__ float fast_rcp(float x){ return __builtin_amdgcn_rcpf(x); }
__device__ __forceinline__ short f2bf(float f){           // RNE float->bf16
  unsigned u = __float_as_uint(f);
  unsigned r = (u + 0x7FFF + ((u>>16)&1)) >> 16;
  return (short)r;
}
__device__ __forceinline__ float bf2f(short s){
  return __uint_as_float(((unsigned)(unsigned short)s) << 16);
}

// ---------------------------------------------------------------------------
// All precompute, 38 blocks x 256 threads.
__global__ __launch_bounds__(256) void k_prep(
    const float* __restrict__ A, const float* __restrict__ g,
    const float* __restrict__ b, const float* __restrict__ Win,
    const float* __restrict__ bin, const float* __restrict__ C,
    short* __restrict__ ApT, float* __restrict__ GA, float* __restrict__ BA,
    short* __restrict__ WA1Th, short* __restrict__ WA1Tl,
    float* __restrict__ binA, short* __restrict__ Cb, short* __restrict__ WinT)
{
  __shared__ float red[4][64], red2[4][64];
  int tid = threadIdx.x;
  int s = tid & 63, part = tid >> 6;
  int blk = blockIdx.x;
  if (blk < NLAYERS){
    int l = blk;
    const float* Al = A + l*HID*STATE;
    const float* Cl = C + l*HID*STATE;
    const float* gl = g + l*HID;
    const float* bl = b + l*HID;
    float ga=0.f, ba=0.f;
    for (int j=part*128; j<(part+1)*128; ++j){
      float a  = Al[j*STATE+s];
      float ap = gl[j]*a;
      ApT[l*HID*STATE + s*HID + j] = f2bf(ap);
      Cb[l*HID*STATE + j*STATE + s] = f2bf(Cl[j*STATE+s]);
      ga += ap; ba = fmaf(bl[j], a, ba);
    }
    red[part][s]=ga; red2[part][s]=ba;
    __syncthreads();
    if (tid < 64){
      GA[l*STATE+s] = red[0][s]+red[1][s]+red[2][s]+red[3][s];
      BA[l*STATE+s] = red2[0][s]+red2[1][s]+red2[2][s]+red2[3][s];
    }
  } else if (blk < NLAYERS+32){
    int k = blk - NLAYERS;
    const float* w = Win + k*HID;
    float acc = 0.f;
    for (int j=part*128; j<(part+1)*128; ++j)
      acc = fmaf(w[j], g[j]*A[j*STATE+s], acc);
    red[part][s] = acc;
    __syncthreads();
    if (tid < 64){
      float v = red[0][s]+red[1][s]+red[2][s]+red[3][s];
      short hi = f2bf(v);
      WA1Th[s*IN_DIM + k] = hi;
      WA1Tl[s*IN_DIM + k] = f2bf(v - bf2f(hi));
    }
  } else if (blk == NLAYERS+32){
    float acc = 0.f;
    for (int j=part*128; j<(part+1)*128; ++j)
      acc = fmaf(bin[j], g[j]*A[j*STATE+s], acc);
    red[part][s] = acc;
    __syncthreads();
    if (tid < 64) binA[s] = red[0][s]+red[1][s]+red[2][s]+red[3][s];
  } else {
    for (int e = tid; e < HID*IN_DIM; e += 256){
      int cc = e >> 5, k = e & 31;
      WinT[cc*IN_DIM + k] = f2bf(Win[k*HID + cc]);
    }
  }
}

// ---------------------------------------------------------------------------
// Fused input via MFMA: h(bf16)=x@Win+bin (vectorized stores via Ysh),
// stats0, U0 (3-term bf16-split, fp16 out). BM=64, grid 1024.
__global__ __launch_bounds__(256) void k_input(const float* __restrict__ x,
    const short* __restrict__ WinT, const float* __restrict__ bin,
    const short* __restrict__ WA1Th, const short* __restrict__ WA1Tl,
    const float* __restrict__ binA,
    const float* __restrict__ GA0, const float* __restrict__ BA0,
    short* __restrict__ h, _Float16* __restrict__ U, float2* __restrict__ stats)
{
  __shared__ __align__(16) short xhi[64][72];
  __shared__ __align__(16) short xlo[64][72];
  __shared__ __align__(16) short Ysh[64][76];
  __shared__ float2 statS[64];
  int m0 = blockIdx.x * 64;
  int tid = threadIdx.x;
  int w = tid >> 6, lane = tid & 63;
  int c = lane & 15, q = lane >> 4;
  int vrow = tid >> 3, vcb = tid & 7;   // vector phase: 32 rows x 8 colblocks
  #pragma unroll
  for (int i=0;i<8;i++){
    int idx = tid + i*256;
    int row = idx >> 5, k = idx & 31;
    float v = x[(size_t)(m0+row)*IN_DIM + k];
    short hi = f2bf(v);
    xhi[row][k] = hi;
    xlo[row][k] = f2bf(v - bf2f(hi));
  }
  __syncthreads();
  short8v ah = *reinterpret_cast<const short8v*>(&xhi[w*16 + c][q*8]);
  short8v al = *reinterpret_cast<const short8v*>(&xlo[w*16 + c][q*8]);
  float sum0=0.f, sq0=0.f, sum1=0.f, sq1=0.f;
  for (int jc=0; jc<HID; jc+=64){
    #pragma unroll
    for (int t=0;t<4;t++){
      short8v bv = *reinterpret_cast<const short8v*>(&WinT[(size_t)(jc + t*16 + c)*IN_DIM + q*8]);
      f32x4 a = {0.f,0.f,0.f,0.f};
      a = __builtin_amdgcn_mfma_f32_16x16x32_bf16(ah, bv, a, 0, 0, 0);
      int col = jc + t*16 + c;
      float bj = bin[col];
      #pragma unroll
      for (int r=0;r<4;r++)
        Ysh[w*16 + q*4 + r][t*16 + c] = f2bf(a[r] + bj);
    }
    __syncthreads();
    #pragma unroll
    for (int rep=0; rep<2; ++rep){
      int row = vrow + rep*32;
      int m = m0 + row;
      short8v yv = *reinterpret_cast<const short8v*>(&Ysh[row][vcb*8]);
      *reinterpret_cast<short8v*>(&h[(size_t)m*HID + jc + vcb*8]) = yv;
      float lsum=0.f, lsq=0.f;
      #pragma unroll
      for (int i=0;i<8;i++){
        float o = bf2f(yv[i]);
        lsum += o; lsq += o*o;
      }
      if (rep) { sum1 += lsum; sq1 += lsq; } else { sum0 += lsum; sq0 += lsq; }
    }
    __syncthreads();
  }
  #pragma unroll
  for (int off=1; off<8; off<<=1){
    sum0 += __shfl_xor(sum0, off);  sq0 += __shfl_xor(sq0, off);
    sum1 += __shfl_xor(sum1, off);  sq1 += __shfl_xor(sq1, off);
  }
  if (vcb == 0){
    float m0v = sum0*(1.f/HID);
    float v0 = sq0*(1.f/HID) - m0v*m0v;
    float2 s0 = make_float2(m0v, rsqrtf(fmaxf(v0,0.f)+EPS));
    stats[m0 + vrow] = s0;  statS[vrow] = s0;
    float m1v = sum1*(1.f/HID);
    float v1 = sq1*(1.f/HID) - m1v*m1v;
    float2 s1 = make_float2(m1v, rsqrtf(fmaxf(v1,0.f)+EPS));
    stats[m0 + 32 + vrow] = s1;  statS[32 + vrow] = s1;
  }
  __syncthreads();
  float mu[4], rs[4];
  #pragma unroll
  for (int r=0;r<4;r++){
    float2 s2 = statS[w*16 + q*4 + r];
    mu[r]=s2.x; rs[r]=s2.y;
  }
  #pragma unroll
  for (int t=0;t<4;t++){
    short8v bh  = *reinterpret_cast<const short8v*>(&WA1Th[(size_t)(t*16 + c)*IN_DIM + q*8]);
    short8v blv = *reinterpret_cast<const short8v*>(&WA1Tl[(size_t)(t*16 + c)*IN_DIM + q*8]);
    f32x4 a = {0.f,0.f,0.f,0.f};
    a = __builtin_amdgcn_mfma_f32_16x16x32_bf16(ah, bh, a, 0, 0, 0);
    a = __builtin_amdgcn_mfma_f32_16x16x32_bf16(al, bh, a, 0, 0, 0);
    a = __builtin_amdgcn_mfma_f32_16x16x32_bf16(ah, blv, a, 0, 0, 0);
    int s = t*16 + c;
    float ga = GA0[s], ba = BA0[s], bA = binA[s];
    #pragma unroll
    for (int r=0;r<4;r++){
      int m = m0 + w*16 + q*4 + r;
      float u = a[r] + bA;
      U[(size_t)m*STATE + s] = (_Float16)fmaf(KTAN, rs[r]*(u - mu[r]*ga) + ba, KTAN);
    }
  }
}

// ---------------------------------------------------------------------------
// U = KTAN*( rstd*(h@A' - mu*GA) + BA ) + KTAN via bf16 MFMA (layers 1..3).
// Hybrid: A (h tile) staged in LDS (latency depth via cooperative prefetch),
// B (ApT, 64KB L1/L2-resident) read direct from global. BM=64, grid 1024.
__global__ __launch_bounds__(256) void k_ugemm(const short* __restrict__ hb,
    const float2* __restrict__ stats, const short* __restrict__ ApT,
    const float* __restrict__ GA, const float* __restrict__ BA,
    _Float16* __restrict__ U)
{
  __shared__ __align__(16) short Hsh[64][72];   // 9.2 KB only
  int m0 = blockIdx.x * 64;
  int tid = threadIdx.x;
  int w = tid >> 6, lane = tid & 63;
  int c = lane & 15, q = lane >> 4;
  float mu[4], rs[4];
  #pragma unroll
  for (int r=0;r<4;r++){
    float2 s2 = stats[m0 + w*16 + q*4 + r];
    mu[r]=s2.x; rs[r]=s2.y;
  }
  f32x4 acc[4] = {{0.f,0.f,0.f,0.f},{0.f,0.f,0.f,0.f},{0.f,0.f,0.f,0.f},{0.f,0.f,0.f,0.f}};
  for (int kc=0; kc<HID; kc+=64){
    #pragma unroll
    for (int p=0;p<2;p++){
      int idx = tid + p*256;
      int row = idx >> 3, kb = idx & 7;
      *reinterpret_cast<short8v*>(&Hsh[row][kb*8]) =
        *reinterpret_cast<const short8v*>(&hb[(size_t)(m0+row)*HID + kc + kb*8]);
    }
    __syncthreads();
    short8v a0 = *reinterpret_cast<const short8v*>(&Hsh[w*16 + c][q*8]);
    short8v a1 = *reinterpret_cast<const short8v*>(&Hsh[w*16 + c][32 + q*8]);
    #pragma unroll
    for (int t=0;t<4;t++){
      short8v b0 = *reinterpret_cast<const short8v*>(&ApT[(size_t)(t*16 + c)*HID + kc + q*8]);
      short8v b1 = *reinterpret_cast<const short8v*>(&ApT[(size_t)(t*16 + c)*HID + kc + 32 + q*8]);
      acc[t] = __builtin_amdgcn_mfma_f32_16x16x32_bf16(a0, b0, acc[t], 0, 0, 0);
      acc[t] = __builtin_amdgcn_mfma_f32_16x16x32_bf16(a1, b1, acc[t], 0, 0, 0);
    }
    __syncthreads();
  }
  #pragma unroll
  for (int t=0;t<4;t++){
    int s = t*16 + c;
    float ga = GA[s], ba = BA[s];
    #pragma unroll
    for (int r=0;r<4;r++){
      int m = m0 + w*16 + q*4 + r;
      U[(size_t)m*STATE + s] = (_Float16)fmaf(KTAN, rs[r]*(acc[t][r] - mu[r]*ga) + ba, KTAN);
    }
  }
}

// ---------------------------------------------------------------------------
// Chunked scan with contraction warmup (R12-verified), U in fp16.
__global__ __launch_bounds__(64) void k_scan(const _Float16* __restrict__ U,
                                             short* __restrict__ H)
{
  int b = blockIdx.x >> 5;
  int p = blockIdx.x & 31;
  int s = threadIdx.x;
  const _Float16* Ub = U + (size_t)b*SEQ*STATE + s;
  short* Hb = H + (size_t)b*SEQ*STATE + s;
  float r = 0.5f;
  float cur[32], nxt[32];
  int t = (p == 0) ? 0 : (p*64 - WARMUP);
  int nsub = (p == 0) ? 2 : 3;
  #pragma unroll
  for (int i=0;i<32;i++) cur[i] = (float)Ub[(t+i)*STATE];
  for (int cidx=0; cidx<nsub; ++cidx){
    bool has_next = (cidx+1 < nsub);
    if (has_next){
      #pragma unroll
      for (int i=0;i<32;i++) nxt[i] = (float)Ub[(t+32+i)*STATE];
    }
    if ((p == 0) || (cidx > 0)){
      #pragma unroll
      for (int i=0;i<32;i++){
        float e = fast_exp2(fmaf(-2.f*KTAN, r, cur[i]));
        r = fast_rcp(1.f + e);
        Hb[(t+i)*STATE] = f2bf(fmaf(-2.f, r, 1.f));
      }
    } else {
      #pragma unroll
      for (int i=0;i<32;i++){
        float e = fast_exp2(fmaf(-2.f*KTAN, r, cur[i]));
        r = fast_rcp(1.f + e);
      }
    }
    if (has_next){
      #pragma unroll
      for (int i=0;i<32;i++) cur[i] = nxt[i];
    }
    t += 32;
  }
}

// ---------------------------------------------------------------------------
// Y epilogue (R12-verified): MFMA -> Ysh(bf16 LDS) -> vectorized short8 h-RMW.
__global__ __launch_bounds__(256) void k_yep4(
    short* __restrict__ h, const short* __restrict__ Hg,
    const short* __restrict__ Cb, const float* __restrict__ Dl,
    const float* __restrict__ gl, const float* __restrict__ bl,
    const float2* __restrict__ stats_in, float2* __restrict__ stats_out)
{
  __shared__ __align__(16) short Hsh[64][72];   // 9.2 KB
  __shared__ __align__(16) short Csh[64][72];   // 9.2 KB
  __shared__ __align__(16) short Ysh[64][76];   // 9.7 KB
  int m0 = blockIdx.x * 64;
  int tid = threadIdx.x;
  int w = tid >> 6, lane = tid & 63;
  int c = lane & 15, q = lane >> 4;
  int vrow = tid >> 3;
  int vcb  = tid & 7;
  #pragma unroll
  for (int p=0;p<2;p++){
    int idx = tid + p*256;
    int row = idx >> 3, kb = idx & 7;
    *reinterpret_cast<short8v*>(&Hsh[row][kb*8]) =
      *reinterpret_cast<const short8v*>(&Hg[(size_t)(m0+row)*STATE + kb*8]);
  }
  float2 sin0 = stats_in[m0 + vrow];
  float2 sin1 = stats_in[m0 + 32 + vrow];
  float sum0=0.f, sq0=0.f, sum1=0.f, sq1=0.f;
  __syncthreads();
  short8v a0 = *reinterpret_cast<const short8v*>(&Hsh[w*16 + c][q*8]);
  short8v a1 = *reinterpret_cast<const short8v*>(&Hsh[w*16 + c][32 + q*8]);
  for (int jc=0; jc<HID; jc+=64){
    #pragma unroll
    for (int p=0;p<2;p++){
      int idx = tid + p*256;
      int col = idx >> 3, kb = idx & 7;
      *reinterpret_cast<short8v*>(&Csh[col][kb*8]) =
        *reinterpret_cast<const short8v*>(&Cb[(size_t)(jc+col)*STATE + kb*8]);
    }
    __syncthreads();
    #pragma unroll
    for (int t=0;t<4;t++){
      short8v b0 = *reinterpret_cast<const short8v*>(&Csh[t*16 + c][q*8]);
      short8v b1 = *reinterpret_cast<const short8v*>(&Csh[t*16 + c][32 + q*8]);
      f32x4 a = {0.f,0.f,0.f,0.f};
      a = __builtin_amdgcn_mfma_f32_16x16x32_bf16(a0, b0, a, 0, 0, 0);
      a = __builtin_amdgcn_mfma_f32_16x16x32_bf16(a1, b1, a, 0, 0, 0);
      #pragma unroll
      for (int r=0;r<4;r++)
        Ysh[w*16 + q*4 + r][t*16 + c] = f2bf(a[r]);
    }
    __syncthreads();
    int col0 = jc + vcb*8;
    float4 gA = CF4(&gl[col0]), gB = CF4(&gl[col0+4]);
    float4 bA = CF4(&bl[col0]), bB = CF4(&bl[col0+4]);
    float4 dA = CF4(&Dl[col0]), dB = CF4(&Dl[col0+4]);
    float ga[8] = {gA.x,gA.y,gA.z,gA.w,gB.x,gB.y,gB.z,gB.w};
    float ba[8] = {bA.x,bA.y,bA.z,bA.w,bB.x,bB.y,bB.z,bB.w};
    float da[8] = {dA.x,dA.y,dA.z,dA.w,dB.x,dB.y,dB.z,dB.w};
    #pragma unroll
    for (int rep=0; rep<2; ++rep){
      int row = vrow + rep*32;
      int m = m0 + row;
      float mu_ = rep ? sin1.x : sin0.x;
      float rs_ = rep ? sin1.y : sin0.y;
      short8v hv = *reinterpret_cast<const short8v*>(&h[(size_t)m*HID + col0]);
      short8v yv = *reinterpret_cast<const short8v*>(&Ysh[row][vcb*8]);
      short8v ov;
      float lsum=0.f, lsq=0.f;
      #pragma unroll
      for (int i=0;i<8;i++){
        float hvf = bf2f(hv[i]);
        float o = hvf + bf2f(yv[i]) + fmaf((hvf-mu_)*rs_, ga[i], ba[i])*da[i];
        ov[i] = f2bf(o);
        lsum += o; lsq += o*o;
      }
      *reinterpret_cast<short8v*>(&h[(size_t)m*HID + col0]) = ov;
      if (rep) { sum1 += lsum; sq1 += lsq; } else { sum0 += lsum; sq0 += lsq; }
    }
  }
  #pragma unroll
  for (int off=1; off<8; off<<=1){
    sum0 += __shfl_xor(sum0, off);  sq0 += __shfl_xor(sq0, off);
    sum1 += __shfl_xor(sum1, off);  sq1 += __shfl_xor(sq1, off);
  }
  if (vcb == 0){
    float m0v = sum0*(1.f/HID);
    float v0 = sq0*(1.f/HID) - m0v*m0v;
    stats_out[m0 + vrow] = make_float2(m0v, rsqrtf(fmaxf(v0,0.f)+EPS));
    float m1v = sum1*(1.f/HID);
    float v1 = sq1*(1.f/HID) - m1v*m1v;
    stats_out[m0 + 32 + vrow] = make_float2(m1v, rsqrtf(fmaxf(v1,0.f)+EPS));
  }
}

// ---------------------------------------------------------------------------
__global__ __launch_bounds__(256) void k_head(const short* __restrict__ h,
   const float2* __restrict__ stats, const float* __restrict__ ng, const float* __restrict__ nb,
   const float* __restrict__ W1, const float* __restrict__ b1,
   const float* __restrict__ W2, const float* __restrict__ b2,
   float* __restrict__ out)
{
  int bb = blockIdx.x;
  int m = bb*SEQ + (SEQ-1);
  int tid = threadIdx.x;
  __shared__ float xs[HID];
  __shared__ float red[8];
  float2 st = stats[m];
  #pragma unroll
  for (int i=0;i<2;i++){
    int j = tid + i*256;
    float v = bf2f(h[(size_t)m*HID + j]);
    xs[j] = fmaf((v - st.x)*st.y, ng[j], nb[j]);
  }
  __syncthreads();
  float acc = b1[tid];
  #pragma unroll 8
  for (int j=0;j<HID;j++) acc = fmaf(xs[j], W1[j*(HID/2) + tid], acc);
  float ge = 0.5f*acc*(1.f + erff(acc*0.70710678118654752f));
  float p0 = ge*W2[tid*2+0];
  float p1 = ge*W2[tid*2+1];
  #pragma unroll
  for (int off=32; off; off>>=1){ p0 += __shfl_down(p0, off); p1 += __shfl_down(p1, off); }
  int wid = tid>>6;
  if ((tid&63)==0){ red[wid*2]=p0; red[wid*2+1]=p1; }
  __syncthreads();
  if (tid==0){
    float o0=b2[0], o1=b2[1];
    #pragma unroll
    for (int w=0;w<4;w++){ o0+=red[w*2]; o1+=red[w*2+1]; }
    out[bb*2+0]=o0; out[bb*2+1]=o1;
  }
}

// ---------------------------------------------------------------------------
extern "C" void kernel_launch(void* const* d_in, const int* in_sizes, int n_in,
                              void* d_out, int out_size, void* d_ws, size_t ws_size,
                              hipStream_t stream)
{
  (void)in_sizes; (void)n_in; (void)out_size; (void)ws_size;
  const float* x   = (const float*)d_in[0];
  const float* Win = (const float*)d_in[1];
  const float* bin = (const float*)d_in[2];
  const float* A   = (const float*)d_in[3];
  const float* C   = (const float*)d_in[4];
  const float* Dv  = (const float*)d_in[5];
  const float* lng = (const float*)d_in[6];
  const float* lnb = (const float*)d_in[7];
  const float* ng  = (const float*)d_in[8];
  const float* nb  = (const float*)d_in[9];
  const float* W1  = (const float*)d_in[10];
  const float* b1  = (const float*)d_in[11];
  const float* W2  = (const float*)d_in[12];
  const float* b2  = (const float*)d_in[13];
  float* out = (float*)d_out;
  char* ws = (char*)d_ws;
  short*     hb   = (short*)(ws + 0);                    //  67,108,864 (bf16)
  _Float16*  Ubuf = (_Float16*)(ws + (size_t)67108864);  //   8,388,608 (fp16)
  short*     Hbuf = (short*)(ws + (size_t)83886080);     //   8,388,608 (bf16)
  float2*    st0  = (float2*)(ws + (size_t)92274688);    //     524,288
  float2*    st1  = (float2*)(ws + (size_t)92798976);    //     524,288
  short*     ApT  = (short*)(ws + (size_t)93323264);     //     262,144 (bf16)
  float*     GAb  = (float*)(ws + (size_t)93585408);     //       1,024
  float*     BAb  = (float*)(ws + (size_t)93586432);     //       1,024
  float*     binAb= (float*)(ws + (size_t)93587456);     //         256
  short*     Cb   = (short*)(ws + (size_t)93587712);     //     262,144 (bf16)
  short*     WinT = (short*)(ws + (size_t)93849856);     //      32,768 (bf16)
  short*     WA1Th= (short*)(ws + (size_t)93882624);     //       4,096 (bf16)
  short*     WA1Tl= (short*)(ws + (size_t)93886720);     //       4,096 (bf16)

  hipLaunchKernelGGL(k_prep,  dim3(38), dim3(256), 0, stream,
      A, lng, lnb, Win, bin, C, ApT, GAb, BAb, WA1Th, WA1Tl, binAb, Cb, WinT);
  hipLaunchKernelGGL(k_input, dim3(NTOK/64), dim3(256), 0, stream,
      x, WinT, bin, WA1Th, WA1Tl, binAb, GAb, BAb, hb, Ubuf, st0);
  float2* scur = st0; float2* snxt = st1;
  for (int l=0; l<NLAYERS; ++l){
    if (l > 0){
      hipLaunchKernelGGL(k_ugemm, dim3(NTOK/64), dim3(256), 0, stream,
          hb, scur, ApT + l*HID*STATE, GAb + l*STATE, BAb + l*STATE, Ubuf);
    }
    hipLaunchKernelGGL(k_scan, dim3(BATCH*NCHUNK), dim3(64), 0, stream, Ubuf, Hbuf);
    hipLaunchKernelGGL(k_yep4, dim3(NTOK/64), dim3(256), 0, stream,
        hb, Hbuf, Cb + l*HID*STATE, Dv + l*HID, lng + l*HID, lnb + l*HID, scur, snxt);
    float2* t = scur; scur = snxt; snxt = t;
  }
  hipLaunchKernelGGL(k_head, dim3(BATCH), dim3(256), 0, stream,
      hb, scur, ng, nb, W1, b1, W2, b2, out);
}

// Round 17
// 246.599 us; speedup vs baseline: 1.2900x; 1.2476x over previous
//
#include <hip/hip_runtime.h>

#define BATCH   32
#define SEQ     2048
#define IN_DIM  32
#define HID     512
#define STATE   64
#define NLAYERS 4
#define NTOK    (BATCH*SEQ)          // 65536
#define EPS     1e-5f
#define KTAN    2.8853900817779268f  // 2*log2(e)
#define NCHUNK  32                   // scan chunks per batch
#define WARMUP  32                   // contraction warmup steps

#define CF4(p) (*reinterpret_cast<const float4*>(p))

typedef __attribute__((ext_vector_type(8))) short short8v;
typedef __attribute__((ext_vector_type(4))) float f32x4;

__device__ __forceinline__ float fast_exp2(float x){ return __builtin_amdgcn_exp2f(x); }
__device__ __forceinline__ float fast_rcp(float x){ return __builtin_amdgcn_rcpf(x); }
__device__ __forceinline__ short f2bf(float f){           // RNE float->bf16
  unsigned u = __float_as_uint(f);
  unsigned r = (u + 0x7FFF + ((u>>16)&1)) >> 16;
  return (short)r;
}
__device__ __forceinline__ float bf2f(short s){
  return __uint_as_float(((unsigned)(unsigned short)s) << 16);
}

// ---------------------------------------------------------------------------
// All precompute, 38 blocks x 256 threads.
__global__ __launch_bounds__(256) void k_prep(
    const float* __restrict__ A, const float* __restrict__ g,
    const float* __restrict__ b, const float* __restrict__ Win,
    const float* __restrict__ bin, const float* __restrict__ C,
    short* __restrict__ ApT, float* __restrict__ GA, float* __restrict__ BA,
    short* __restrict__ WA1Th, short* __restrict__ WA1Tl,
    float* __restrict__ binA, short* __restrict__ Cb, short* __restrict__ WinT)
{
  __shared__ float red[4][64], red2[4][64];
  int tid = threadIdx.x;
  int s = tid & 63, part = tid >> 6;
  int blk = blockIdx.x;
  if (blk < NLAYERS){
    int l = blk;
    const float* Al = A + l*HID*STATE;
    const float* Cl = C + l*HID*STATE;
    const float* gl = g + l*HID;
    const float* bl = b + l*HID;
    float ga=0.f, ba=0.f;
    for (int j=part*128; j<(part+1)*128; ++j){
      float a  = Al[j*STATE+s];
      float ap = gl[j]*a;
      ApT[l*HID*STATE + s*HID + j] = f2bf(ap);
      Cb[l*HID*STATE + j*STATE + s] = f2bf(Cl[j*STATE+s]);
      ga += ap; ba = fmaf(bl[j], a, ba);
    }
    red[part][s]=ga; red2[part][s]=ba;
    __syncthreads();
    if (tid < 64){
      GA[l*STATE+s] = red[0][s]+red[1][s]+red[2][s]+red[3][s];
      BA[l*STATE+s] = red2[0][s]+red2[1][s]+red2[2][s]+red2[3][s];
    }
  } else if (blk < NLAYERS+32){
    int k = blk - NLAYERS;
    const float* w = Win + k*HID;
    float acc = 0.f;
    for (int j=part*128; j<(part+1)*128; ++j)
      acc = fmaf(w[j], g[j]*A[j*STATE+s], acc);
    red[part][s] = acc;
    __syncthreads();
    if (tid < 64){
      float v = red[0][s]+red[1][s]+red[2][s]+red[3][s];
      short hi = f2bf(v);
      WA1Th[s*IN_DIM + k] = hi;
      WA1Tl[s*IN_DIM + k] = f2bf(v - bf2f(hi));
    }
  } else if (blk == NLAYERS+32){
    float acc = 0.f;
    for (int j=part*128; j<(part+1)*128; ++j)
      acc = fmaf(bin[j], g[j]*A[j*STATE+s], acc);
    red[part][s] = acc;
    __syncthreads();
    if (tid < 64) binA[s] = red[0][s]+red[1][s]+red[2][s]+red[3][s];
  } else {
    for (int e = tid; e < HID*IN_DIM; e += 256){
      int cc = e >> 5, k = e & 31;
      WinT[cc*IN_DIM + k] = f2bf(Win[k*HID + cc]);
    }
  }
}

// ---------------------------------------------------------------------------
// Fused input via MFMA: h(bf16)=x@Win+bin (vectorized stores via Ysh),
// stats0, U0 (3-term bf16-split, fp16 out). BM=64, grid 1024. (R12-verified)
__global__ __launch_bounds__(256) void k_input(const float* __restrict__ x,
    const short* __restrict__ WinT, const float* __restrict__ bin,
    const short* __restrict__ WA1Th, const short* __restrict__ WA1Tl,
    const float* __restrict__ binA,
    const float* __restrict__ GA0, const float* __restrict__ BA0,
    short* __restrict__ h, _Float16* __restrict__ U, float2* __restrict__ stats)
{
  __shared__ __align__(16) short xhi[64][72];
  __shared__ __align__(16) short xlo[64][72];
  __shared__ __align__(16) short Ysh[64][76];
  __shared__ float2 statS[64];
  int m0 = blockIdx.x * 64;
  int tid = threadIdx.x;
  int w = tid >> 6, lane = tid & 63;
  int c = lane & 15, q = lane >> 4;
  int vrow = tid >> 3, vcb = tid & 7;   // vector phase: 32 rows x 8 colblocks
  #pragma unroll
  for (int i=0;i<8;i++){
    int idx = tid + i*256;
    int row = idx >> 5, k = idx & 31;
    float v = x[(size_t)(m0+row)*IN_DIM + k];
    short hi = f2bf(v);
    xhi[row][k] = hi;
    xlo[row][k] = f2bf(v - bf2f(hi));
  }
  __syncthreads();
  short8v ah = *reinterpret_cast<const short8v*>(&xhi[w*16 + c][q*8]);
  short8v al = *reinterpret_cast<const short8v*>(&xlo[w*16 + c][q*8]);
  float sum0=0.f, sq0=0.f, sum1=0.f, sq1=0.f;
  for (int jc=0; jc<HID; jc+=64){
    #pragma unroll
    for (int t=0;t<4;t++){
      short8v bv = *reinterpret_cast<const short8v*>(&WinT[(size_t)(jc + t*16 + c)*IN_DIM + q*8]);
      f32x4 a = {0.f,0.f,0.f,0.f};
      a = __builtin_amdgcn_mfma_f32_16x16x32_bf16(ah, bv, a, 0, 0, 0);
      int col = jc + t*16 + c;
      float bj = bin[col];
      #pragma unroll
      for (int r=0;r<4;r++)
        Ysh[w*16 + q*4 + r][t*16 + c] = f2bf(a[r] + bj);
    }
    __syncthreads();
    #pragma unroll
    for (int rep=0; rep<2; ++rep){
      int row = vrow + rep*32;
      int m = m0 + row;
      short8v yv = *reinterpret_cast<const short8v*>(&Ysh[row][vcb*8]);
      *reinterpret_cast<short8v*>(&h[(size_t)m*HID + jc + vcb*8]) = yv;
      float lsum=0.f, lsq=0.f;
      #pragma unroll
      for (int i=0;i<8;i++){
        float o = bf2f(yv[i]);
        lsum += o; lsq += o*o;
      }
      if (rep) { sum1 += lsum; sq1 += lsq; } else { sum0 += lsum; sq0 += lsq; }
    }
    __syncthreads();
  }
  #pragma unroll
  for (int off=1; off<8; off<<=1){
    sum0 += __shfl_xor(sum0, off);  sq0 += __shfl_xor(sq0, off);
    sum1 += __shfl_xor(sum1, off);  sq1 += __shfl_xor(sq1, off);
  }
  if (vcb == 0){
    float m0v = sum0*(1.f/HID);
    float v0 = sq0*(1.f/HID) - m0v*m0v;
    float2 s0 = make_float2(m0v, rsqrtf(fmaxf(v0,0.f)+EPS));
    stats[m0 + vrow] = s0;  statS[vrow] = s0;
    float m1v = sum1*(1.f/HID);
    float v1 = sq1*(1.f/HID) - m1v*m1v;
    float2 s1 = make_float2(m1v, rsqrtf(fmaxf(v1,0.f)+EPS));
    stats[m0 + 32 + vrow] = s1;  statS[32 + vrow] = s1;
  }
  __syncthreads();
  float mu[4], rs[4];
  #pragma unroll
  for (int r=0;r<4;r++){
    float2 s2 = statS[w*16 + q*4 + r];
    mu[r]=s2.x; rs[r]=s2.y;
  }
  #pragma unroll
  for (int t=0;t<4;t++){
    short8v bh  = *reinterpret_cast<const short8v*>(&WA1Th[(size_t)(t*16 + c)*IN_DIM + q*8]);
    short8v blv = *reinterpret_cast<const short8v*>(&WA1Tl[(size_t)(t*16 + c)*IN_DIM + q*8]);
    f32x4 a = {0.f,0.f,0.f,0.f};
    a = __builtin_amdgcn_mfma_f32_16x16x32_bf16(ah, bh, a, 0, 0, 0);
    a = __builtin_amdgcn_mfma_f32_16x16x32_bf16(al, bh, a, 0, 0, 0);
    a = __builtin_amdgcn_mfma_f32_16x16x32_bf16(ah, blv, a, 0, 0, 0);
    int s = t*16 + c;
    float ga = GA0[s], ba = BA0[s], bA = binA[s];
    #pragma unroll
    for (int r=0;r<4;r++){
      int m = m0 + w*16 + q*4 + r;
      float u = a[r] + bA;
      U[(size_t)m*STATE + s] = (_Float16)fmaf(KTAN, rs[r]*(u - mu[r]*ga) + ba, KTAN);
    }
  }
}

// ---------------------------------------------------------------------------
// U = KTAN*( rstd*(h@A' - mu*GA) + BA ) + KTAN via bf16 MFMA (layers 1..3).
// R12-verified structure: BOTH operands barrier-staged through LDS (the
// stage->barrier->consume shape is the software pipeline; B-direct variants
// measured 40 µs vs this one's ~25). BM=64, grid 1024, fp16 U out.
__global__ __launch_bounds__(256) void k_ugemm(const short* __restrict__ hb,
    const float2* __restrict__ stats, const short* __restrict__ ApT,
    const float* __restrict__ GA, const float* __restrict__ BA,
    _Float16* __restrict__ U)
{
  __shared__ __align__(16) short Hsh[64][72];
  __shared__ __align__(16) short Bsh[64][72];
  int m0 = blockIdx.x * 64;
  int tid = threadIdx.x;
  int w = tid >> 6, lane = tid & 63;
  int c = lane & 15, q = lane >> 4;
  float mu[4], rs[4];
  #pragma unroll
  for (int r=0;r<4;r++){
    float2 s2 = stats[m0 + w*16 + q*4 + r];
    mu[r]=s2.x; rs[r]=s2.y;
  }
  f32x4 acc[4] = {{0.f,0.f,0.f,0.f},{0.f,0.f,0.f,0.f},{0.f,0.f,0.f,0.f},{0.f,0.f,0.f,0.f}};
  for (int kc=0; kc<HID; kc+=64){
    #pragma unroll
    for (int p=0;p<2;p++){
      int idx = tid + p*256;
      int row = idx >> 3, kb = idx & 7;
      *reinterpret_cast<short8v*>(&Hsh[row][kb*8]) =
        *reinterpret_cast<const short8v*>(&hb[(size_t)(m0+row)*HID + kc + kb*8]);
      *reinterpret_cast<short8v*>(&Bsh[row][kb*8]) =
        *reinterpret_cast<const short8v*>(&ApT[(size_t)row*HID + kc + kb*8]);
    }
    __syncthreads();
    short8v a0 = *reinterpret_cast<const short8v*>(&Hsh[w*16 + c][q*8]);
    short8v a1 = *reinterpret_cast<const short8v*>(&Hsh[w*16 + c][32 + q*8]);
    #pragma unroll
    for (int t=0;t<4;t++){
      short8v b0 = *reinterpret_cast<const short8v*>(&Bsh[t*16 + c][q*8]);
      short8v b1 = *reinterpret_cast<const short8v*>(&Bsh[t*16 + c][32 + q*8]);
      acc[t] = __builtin_amdgcn_mfma_f32_16x16x32_bf16(a0, b0, acc[t], 0, 0, 0);
      acc[t] = __builtin_amdgcn_mfma_f32_16x16x32_bf16(a1, b1, acc[t], 0, 0, 0);
    }
    __syncthreads();
  }
  #pragma unroll
  for (int t=0;t<4;t++){
    int s = t*16 + c;
    float ga = GA[s], ba = BA[s];
    #pragma unroll
    for (int r=0;r<4;r++){
      int m = m0 + w*16 + q*4 + r;
      U[(size_t)m*STATE + s] = (_Float16)fmaf(KTAN, rs[r]*(acc[t][r] - mu[r]*ga) + ba, KTAN);
    }
  }
}

// ---------------------------------------------------------------------------
// Chunked scan with contraction warmup (R12-verified), U in fp16.
__global__ __launch_bounds__(64) void k_scan(const _Float16* __restrict__ U,
                                             short* __restrict__ H)
{
  int b = blockIdx.x >> 5;
  int p = blockIdx.x & 31;
  int s = threadIdx.x;
  const _Float16* Ub = U + (size_t)b*SEQ*STATE + s;
  short* Hb = H + (size_t)b*SEQ*STATE + s;
  float r = 0.5f;
  float cur[32], nxt[32];
  int t = (p == 0) ? 0 : (p*64 - WARMUP);
  int nsub = (p == 0) ? 2 : 3;
  #pragma unroll
  for (int i=0;i<32;i++) cur[i] = (float)Ub[(t+i)*STATE];
  for (int cidx=0; cidx<nsub; ++cidx){
    bool has_next = (cidx+1 < nsub);
    if (has_next){
      #pragma unroll
      for (int i=0;i<32;i++) nxt[i] = (float)Ub[(t+32+i)*STATE];
    }
    if ((p == 0) || (cidx > 0)){
      #pragma unroll
      for (int i=0;i<32;i++){
        float e = fast_exp2(fmaf(-2.f*KTAN, r, cur[i]));
        r = fast_rcp(1.f + e);
        Hb[(t+i)*STATE] = f2bf(fmaf(-2.f, r, 1.f));
      }
    } else {
      #pragma unroll
      for (int i=0;i<32;i++){
        float e = fast_exp2(fmaf(-2.f*KTAN, r, cur[i]));
        r = fast_rcp(1.f + e);
      }
    }
    if (has_next){
      #pragma unroll
      for (int i=0;i<32;i++) cur[i] = nxt[i];
    }
    t += 32;
  }
}

// ---------------------------------------------------------------------------
// Y epilogue (R12-verified): MFMA -> Ysh(bf16 LDS) -> vectorized short8 h-RMW.
__global__ __launch_bounds__(256) void k_yep4(
    short* __restrict__ h, const short* __restrict__ Hg,
    const short* __restrict__ Cb, const float* __restrict__ Dl,
    const float* __restrict__ gl, const float* __restrict__ bl,
    const float2* __restrict__ stats_in, float2* __restrict__ stats_out)
{
  __shared__ __align__(16) short Hsh[64][72];   // 9.2 KB
  __shared__ __align__(16) short Csh[64][72];   // 9.2 KB
  __shared__ __align__(16) short Ysh[64][76];   // 9.7 KB
  int m0 = blockIdx.x * 64;
  int tid = threadIdx.x;
  int w = tid >> 6, lane = tid & 63;
  int c = lane & 15, q = lane >> 4;
  int vrow = tid >> 3;
  int vcb  = tid & 7;
  #pragma unroll
  for (int p=0;p<2;p++){
    int idx = tid + p*256;
    int row = idx >> 3, kb = idx & 7;
    *reinterpret_cast<short8v*>(&Hsh[row][kb*8]) =
      *reinterpret_cast<const short8v*>(&Hg[(size_t)(m0+row)*STATE + kb*8]);
  }
  float2 sin0 = stats_in[m0 + vrow];
  float2 sin1 = stats_in[m0 + 32 + vrow];
  float sum0=0.f, sq0=0.f, sum1=0.f, sq1=0.f;
  __syncthreads();
  short8v a0 = *reinterpret_cast<const short8v*>(&Hsh[w*16 + c][q*8]);
  short8v a1 = *reinterpret_cast<const short8v*>(&Hsh[w*16 + c][32 + q*8]);
  for (int jc=0; jc<HID; jc+=64){
    #pragma unroll
    for (int p=0;p<2;p++){
      int idx = tid + p*256;
      int col = idx >> 3, kb = idx & 7;
      *reinterpret_cast<short8v*>(&Csh[col][kb*8]) =
        *reinterpret_cast<const short8v*>(&Cb[(size_t)(jc+col)*STATE + kb*8]);
    }
    __syncthreads();
    #pragma unroll
    for (int t=0;t<4;t++){
      short8v b0 = *reinterpret_cast<const short8v*>(&Csh[t*16 + c][q*8]);
      short8v b1 = *reinterpret_cast<const short8v*>(&Csh[t*16 + c][32 + q*8]);
      f32x4 a = {0.f,0.f,0.f,0.f};
      a = __builtin_amdgcn_mfma_f32_16x16x32_bf16(a0, b0, a, 0, 0, 0);
      a = __builtin_amdgcn_mfma_f32_16x16x32_bf16(a1, b1, a, 0, 0, 0);
      #pragma unroll
      for (int r=0;r<4;r++)
        Ysh[w*16 + q*4 + r][t*16 + c] = f2bf(a[r]);
    }
    __syncthreads();
    int col0 = jc + vcb*8;
    float4 gA = CF4(&gl[col0]), gB = CF4(&gl[col0+4]);
    float4 bA = CF4(&bl[col0]), bB = CF4(&bl[col0+4]);
    float4 dA = CF4(&Dl[col0]), dB = CF4(&Dl[col0+4]);
    float ga[8] = {gA.x,gA.y,gA.z,gA.w,gB.x,gB.y,gB.z,gB.w};
    float ba[8] = {bA.x,bA.y,bA.z,bA.w,bB.x,bB.y,bB.z,bB.w};
    float da[8] = {dA.x,dA.y,dA.z,dA.w,dB.x,dB.y,dB.z,dB.w};
    #pragma unroll
    for (int rep=0; rep<2; ++rep){
      int row = vrow + rep*32;
      int m = m0 + row;
      float mu_ = rep ? sin1.x : sin0.x;
      float rs_ = rep ? sin1.y : sin0.y;
      short8v hv = *reinterpret_cast<const short8v*>(&h[(size_t)m*HID + col0]);
      short8v yv = *reinterpret_cast<const short8v*>(&Ysh[row][vcb*8]);
      short8v ov;
      float lsum=0.f, lsq=0.f;
      #pragma unroll
      for (int i=0;i<8;i++){
        float hvf = bf2f(hv[i]);
        float o = hvf + bf2f(yv[i]) + fmaf((hvf-mu_)*rs_, ga[i], ba[i])*da[i];
        ov[i] = f2bf(o);
        lsum += o; lsq += o*o;
      }
      *reinterpret_cast<short8v*>(&h[(size_t)m*HID + col0]) = ov;
      if (rep) { sum1 += lsum; sq1 += lsq; } else { sum0 += lsum; sq0 += lsq; }
    }
  }
  #pragma unroll
  for (int off=1; off<8; off<<=1){
    sum0 += __shfl_xor(sum0, off);  sq0 += __shfl_xor(sq0, off);
    sum1 += __shfl_xor(sum1, off);  sq1 += __shfl_xor(sq1, off);
  }
  if (vcb == 0){
    float m0v = sum0*(1.f/HID);
    float v0 = sq0*(1.f/HID) - m0v*m0v;
    stats_out[m0 + vrow] = make_float2(m0v, rsqrtf(fmaxf(v0,0.f)+EPS));
    float m1v = sum1*(1.f/HID);
    float v1 = sq1*(1.f/HID) - m1v*m1v;
    stats_out[m0 + 32 + vrow] = make_float2(m1v, rsqrtf(fmaxf(v1,0.f)+EPS));
  }
}

// ---------------------------------------------------------------------------
__global__ __launch_bounds__(256) void k_head(const short* __restrict__ h,
   const float2* __restrict__ stats, const float* __restrict__ ng, const float* __restrict__ nb,
   const float* __restrict__ W1, const float* __restrict__ b1,
   const float* __restrict__ W2, const float* __restrict__ b2,
   float* __restrict__ out)
{
  int bb = blockIdx.x;
  int m = bb*SEQ + (SEQ-1);
  int tid = threadIdx.x;
  __shared__ float xs[HID];
  __shared__ float red[8];
  float2 st = stats[m];
  #pragma unroll
  for (int i=0;i<2;i++){
    int j = tid + i*256;
    float v = bf2f(h[(size_t)m*HID + j]);
    xs[j] = fmaf((v - st.x)*st.y, ng[j], nb[j]);
  }
  __syncthreads();
  float acc = b1[tid];
  #pragma unroll 8
  for (int j=0;j<HID;j++) acc = fmaf(xs[j], W1[j*(HID/2) + tid], acc);
  float ge = 0.5f*acc*(1.f + erff(acc*0.70710678118654752f));
  float p0 = ge*W2[tid*2+0];
  float p1 = ge*W2[tid*2+1];
  #pragma unroll
  for (int off=32; off; off>>=1){ p0 += __shfl_down(p0, off); p1 += __shfl_down(p1, off); }
  int wid = tid>>6;
  if ((tid&63)==0){ red[wid*2]=p0; red[wid*2+1]=p1; }
  __syncthreads();
  if (tid==0){
    float o0=b2[0], o1=b2[1];
    #pragma unroll
    for (int w=0;w<4;w++){ o0+=red[w*2]; o1+=red[w*2+1]; }
    out[bb*2+0]=o0; out[bb*2+1]=o1;
  }
}

// ---------------------------------------------------------------------------
extern "C" void kernel_launch(void* const* d_in, const int* in_sizes, int n_in,
                              void* d_out, int out_size, void* d_ws, size_t ws_size,
                              hipStream_t stream)
{
  (void)in_sizes; (void)n_in; (void)out_size; (void)ws_size;
  const float* x   = (const float*)d_in[0];
  const float* Win = (const float*)d_in[1];
  const float* bin = (const float*)d_in[2];
  const float* A   = (const float*)d_in[3];
  const float* C   = (const float*)d_in[4];
  const float* Dv  = (const float*)d_in[5];
  const float* lng = (const float*)d_in[6];
  const float* lnb = (const float*)d_in[7];
  const float* ng  = (const float*)d_in[8];
  const float* nb  = (const float*)d_in[9];
  const float* W1  = (const float*)d_in[10];
  const float* b1  = (const float*)d_in[11];
  const float* W2  = (const float*)d_in[12];
  const float* b2  = (const float*)d_in[13];
  float* out = (float*)d_out;
  char* ws = (char*)d_ws;
  short*     hb   = (short*)(ws + 0);                    //  67,108,864 (bf16)
  _Float16*  Ubuf = (_Float16*)(ws + (size_t)67108864);  //   8,388,608 (fp16)
  short*     Hbuf = (short*)(ws + (size_t)83886080);     //   8,388,608 (bf16)
  float2*    st0  = (float2*)(ws + (size_t)92274688);    //     524,288
  float2*    st1  = (float2*)(ws + (size_t)92798976);    //     524,288
  short*     ApT  = (short*)(ws + (size_t)93323264);     //     262,144 (bf16)
  float*     GAb  = (float*)(ws + (size_t)93585408);     //       1,024
  float*     BAb  = (float*)(ws + (size_t)93586432);     //       1,024
  float*     binAb= (float*)(ws + (size_t)93587456);     //         256
  short*     Cb   = (short*)(ws + (size_t)93587712);     //     262,144 (bf16)
  short*     WinT = (short*)(ws + (size_t)93849856);     //      32,768 (bf16)
  short*     WA1Th= (short*)(ws + (size_t)93882624);     //       4,096 (bf16)
  short*     WA1Tl= (short*)(ws + (size_t)93886720);     //       4,096 (bf16)

  hipLaunchKernelGGL(k_prep,  dim3(38), dim3(256), 0, stream,
      A, lng, lnb, Win, bin, C, ApT, GAb, BAb, WA1Th, WA1Tl, binAb, Cb, WinT);
  hipLaunchKernelGGL(k_input, dim3(NTOK/64), dim3(256), 0, stream,
      x, WinT, bin, WA1Th, WA1Tl, binAb, GAb, BAb, hb, Ubuf, st0);
  float2* scur = st0; float2* snxt = st1;
  for (int l=0; l<NLAYERS; ++l){
    if (l > 0){
      hipLaunchKernelGGL(k_ugemm, dim3(NTOK/64), dim3(256), 0, stream,
          hb, scur, ApT + l*HID*STATE, GAb + l*STATE, BAb + l*STATE, Ubuf);
    }
    hipLaunchKernelGGL(k_scan, dim3(BATCH*NCHUNK), dim3(64), 0, stream, Ubuf, Hbuf);
    hipLaunchKernelGGL(k_yep4, dim3(NTOK/64), dim3(256), 0, stream,
        hb, Hbuf, Cb + l*HID*STATE, Dv + l*HID, lng + l*HID, lnb + l*HID, scur, snxt);
    float2* t = scur; scur = snxt; snxt = t;
  }
  hipLaunchKernelGGL(k_head, dim3(BATCH), dim3(256), 0, stream,
      hb, scur, ng, nb, W1, b1, W2, b2, out);
}

// Round 18
// 245.629 us; speedup vs baseline: 1.2950x; 1.0039x over previous
//
#include <hip/hip_runtime.h>

#define BATCH   32
#define SEQ     2048
#define IN_DIM  32
#define HID     512
#define STATE   64
#define NLAYERS 4
#define NTOK    (BATCH*SEQ)          // 65536
#define EPS     1e-5f
#define KTAN    2.8853900817779268f  // 2*log2(e)
#define NCHUNK  32                   // scan chunks per batch
#define WARMUP  32                   // contraction warmup steps

#define CF4(p) (*reinterpret_cast<const float4*>(p))

typedef __attribute__((ext_vector_type(8))) short short8v;
typedef __attribute__((ext_vector_type(4))) float f32x4;

__device__ __forceinline__ float fast_exp2(float x){ return __builtin_amdgcn_exp2f(x); }
__device__ __forceinline__ float fast_rcp(float x){ return __builtin_amdgcn_rcpf(x); }
__device__ __forceinline__ short f2bf(float f){           // RNE float->bf16
  unsigned u = __float_as_uint(f);
  unsigned r = (u + 0x7FFF + ((u>>16)&1)) >> 16;
  return (short)r;
}
__device__ __forceinline__ float bf2f(short s){
  return __uint_as_float(((unsigned)(unsigned short)s) << 16);
}

// ---------------------------------------------------------------------------
// All precompute, 38 blocks x 256 threads.
__global__ __launch_bounds__(256) void k_prep(
    const float* __restrict__ A, const float* __restrict__ g,
    const float* __restrict__ b, const float* __restrict__ Win,
    const float* __restrict__ bin, const float* __restrict__ C,
    short* __restrict__ ApT, float* __restrict__ GA, float* __restrict__ BA,
    short* __restrict__ WA1Th, short* __restrict__ WA1Tl,
    float* __restrict__ binA, short* __restrict__ Cb, short* __restrict__ WinT)
{
  __shared__ float red[4][64], red2[4][64];
  int tid = threadIdx.x;
  int s = tid & 63, part = tid >> 6;
  int blk = blockIdx.x;
  if (blk < NLAYERS){
    int l = blk;
    const float* Al = A + l*HID*STATE;
    const float* Cl = C + l*HID*STATE;
    const float* gl = g + l*HID;
    const float* bl = b + l*HID;
    float ga=0.f, ba=0.f;
    for (int j=part*128; j<(part+1)*128; ++j){
      float a  = Al[j*STATE+s];
      float ap = gl[j]*a;
      ApT[l*HID*STATE + s*HID + j] = f2bf(ap);
      Cb[l*HID*STATE + j*STATE + s] = f2bf(Cl[j*STATE+s]);
      ga += ap; ba = fmaf(bl[j], a, ba);
    }
    red[part][s]=ga; red2[part][s]=ba;
    __syncthreads();
    if (tid < 64){
      GA[l*STATE+s] = red[0][s]+red[1][s]+red[2][s]+red[3][s];
      BA[l*STATE+s] = red2[0][s]+red2[1][s]+red2[2][s]+red2[3][s];
    }
  } else if (blk < NLAYERS+32){
    int k = blk - NLAYERS;
    const float* w = Win + k*HID;
    float acc = 0.f;
    for (int j=part*128; j<(part+1)*128; ++j)
      acc = fmaf(w[j], g[j]*A[j*STATE+s], acc);
    red[part][s] = acc;
    __syncthreads();
    if (tid < 64){
      float v = red[0][s]+red[1][s]+red[2][s]+red[3][s];
      short hi = f2bf(v);
      WA1Th[s*IN_DIM + k] = hi;
      WA1Tl[s*IN_DIM + k] = f2bf(v - bf2f(hi));
    }
  } else if (blk == NLAYERS+32){
    float acc = 0.f;
    for (int j=part*128; j<(part+1)*128; ++j)
      acc = fmaf(bin[j], g[j]*A[j*STATE+s], acc);
    red[part][s] = acc;
    __syncthreads();
    if (tid < 64) binA[s] = red[0][s]+red[1][s]+red[2][s]+red[3][s];
  } else {
    for (int e = tid; e < HID*IN_DIM; e += 256){
      int cc = e >> 5, k = e & 31;
      WinT[cc*IN_DIM + k] = f2bf(Win[k*HID + cc]);
    }
  }
}

// ---------------------------------------------------------------------------
// Fused input via MFMA: h(bf16)=x@Win+bin, stats0, U0 (3-term split, fp16).
// Ysh double-buffered: one barrier per 64-col chunk (barrier(i) orders
// store(i-1) reads before MFMA(i+1) overwrites the same buffer).
__global__ __launch_bounds__(256) void k_input(const float* __restrict__ x,
    const short* __restrict__ WinT, const float* __restrict__ bin,
    const short* __restrict__ WA1Th, const short* __restrict__ WA1Tl,
    const float* __restrict__ binA,
    const float* __restrict__ GA0, const float* __restrict__ BA0,
    short* __restrict__ h, _Float16* __restrict__ U, float2* __restrict__ stats)
{
  __shared__ __align__(16) short xhi[64][72];
  __shared__ __align__(16) short xlo[64][72];
  __shared__ __align__(16) short Ysh[2][64][76];
  __shared__ float2 statS[64];
  int m0 = blockIdx.x * 64;
  int tid = threadIdx.x;
  int w = tid >> 6, lane = tid & 63;
  int c = lane & 15, q = lane >> 4;
  int vrow = tid >> 3, vcb = tid & 7;   // vector phase: 32 rows x 8 colblocks
  #pragma unroll
  for (int i=0;i<8;i++){
    int idx = tid + i*256;
    int row = idx >> 5, k = idx & 31;
    float v = x[(size_t)(m0+row)*IN_DIM + k];
    short hi = f2bf(v);
    xhi[row][k] = hi;
    xlo[row][k] = f2bf(v - bf2f(hi));
  }
  __syncthreads();
  short8v ah = *reinterpret_cast<const short8v*>(&xhi[w*16 + c][q*8]);
  short8v al = *reinterpret_cast<const short8v*>(&xlo[w*16 + c][q*8]);
  float sum0=0.f, sq0=0.f, sum1=0.f, sq1=0.f;
  for (int jc=0; jc<HID; jc+=64){
    int cb = (jc >> 6) & 1;
    #pragma unroll
    for (int t=0;t<4;t++){
      short8v bv = *reinterpret_cast<const short8v*>(&WinT[(size_t)(jc + t*16 + c)*IN_DIM + q*8]);
      f32x4 a = {0.f,0.f,0.f,0.f};
      a = __builtin_amdgcn_mfma_f32_16x16x32_bf16(ah, bv, a, 0, 0, 0);
      int col = jc + t*16 + c;
      float bj = bin[col];
      #pragma unroll
      for (int r=0;r<4;r++)
        Ysh[cb][w*16 + q*4 + r][t*16 + c] = f2bf(a[r] + bj);
    }
    __syncthreads();
    #pragma unroll
    for (int rep=0; rep<2; ++rep){
      int row = vrow + rep*32;
      int m = m0 + row;
      short8v yv = *reinterpret_cast<const short8v*>(&Ysh[cb][row][vcb*8]);
      *reinterpret_cast<short8v*>(&h[(size_t)m*HID + jc + vcb*8]) = yv;
      float lsum=0.f, lsq=0.f;
      #pragma unroll
      for (int i=0;i<8;i++){
        float o = bf2f(yv[i]);
        lsum += o; lsq += o*o;
      }
      if (rep) { sum1 += lsum; sq1 += lsq; } else { sum0 += lsum; sq0 += lsq; }
    }
  }
  #pragma unroll
  for (int off=1; off<8; off<<=1){
    sum0 += __shfl_xor(sum0, off);  sq0 += __shfl_xor(sq0, off);
    sum1 += __shfl_xor(sum1, off);  sq1 += __shfl_xor(sq1, off);
  }
  if (vcb == 0){
    float m0v = sum0*(1.f/HID);
    float v0 = sq0*(1.f/HID) - m0v*m0v;
    float2 s0 = make_float2(m0v, rsqrtf(fmaxf(v0,0.f)+EPS));
    stats[m0 + vrow] = s0;  statS[vrow] = s0;
    float m1v = sum1*(1.f/HID);
    float v1 = sq1*(1.f/HID) - m1v*m1v;
    float2 s1 = make_float2(m1v, rsqrtf(fmaxf(v1,0.f)+EPS));
    stats[m0 + 32 + vrow] = s1;  statS[32 + vrow] = s1;
  }
  __syncthreads();
  float mu[4], rs[4];
  #pragma unroll
  for (int r=0;r<4;r++){
    float2 s2 = statS[w*16 + q*4 + r];
    mu[r]=s2.x; rs[r]=s2.y;
  }
  #pragma unroll
  for (int t=0;t<4;t++){
    short8v bh  = *reinterpret_cast<const short8v*>(&WA1Th[(size_t)(t*16 + c)*IN_DIM + q*8]);
    short8v blv = *reinterpret_cast<const short8v*>(&WA1Tl[(size_t)(t*16 + c)*IN_DIM + q*8]);
    f32x4 a = {0.f,0.f,0.f,0.f};
    a = __builtin_amdgcn_mfma_f32_16x16x32_bf16(ah, bh, a, 0, 0, 0);
    a = __builtin_amdgcn_mfma_f32_16x16x32_bf16(al, bh, a, 0, 0, 0);
    a = __builtin_amdgcn_mfma_f32_16x16x32_bf16(ah, blv, a, 0, 0, 0);
    int s = t*16 + c;
    float ga = GA0[s], ba = BA0[s], bA = binA[s];
    #pragma unroll
    for (int r=0;r<4;r++){
      int m = m0 + w*16 + q*4 + r;
      float u = a[r] + bA;
      U[(size_t)m*STATE + s] = (_Float16)fmaf(KTAN, rs[r]*(u - mu[r]*ga) + ba, KTAN);
    }
  }
}

// ---------------------------------------------------------------------------
// U = KTAN*( rstd*(h@A' - mu*GA) + BA ) + KTAN via bf16 MFMA (layers 1..3).
// Double-buffered LDS (Hsh[2]/Bsh[2]): next chunk's staging issues BEFORE the
// current chunk's MFMAs; one barrier per K-chunk. fp16 U out.
__global__ __launch_bounds__(256) void k_ugemm(const short* __restrict__ hb,
    const float2* __restrict__ stats, const short* __restrict__ ApT,
    const float* __restrict__ GA, const float* __restrict__ BA,
    _Float16* __restrict__ U)
{
  __shared__ __align__(16) short Hsh[2][64][72];   // 18.4 KB
  __shared__ __align__(16) short Bsh[2][64][72];   // 18.4 KB
  int m0 = blockIdx.x * 64;
  int tid = threadIdx.x;
  int w = tid >> 6, lane = tid & 63;
  int c = lane & 15, q = lane >> 4;
  int srow = tid >> 3, skb = tid & 7;   // staging role: 2 passes of 256
  float mu[4], rs[4];
  #pragma unroll
  for (int r=0;r<4;r++){
    float2 s2 = stats[m0 + w*16 + q*4 + r];
    mu[r]=s2.x; rs[r]=s2.y;
  }
  // prologue: stage chunk 0 into buffer 0
  #pragma unroll
  for (int p=0;p<2;p++){
    int idx = tid + p*256;
    int row = idx >> 3, kb = idx & 7;
    *reinterpret_cast<short8v*>(&Hsh[0][row][kb*8]) =
      *reinterpret_cast<const short8v*>(&hb[(size_t)(m0+row)*HID + kb*8]);
    *reinterpret_cast<short8v*>(&Bsh[0][row][kb*8]) =
      *reinterpret_cast<const short8v*>(&ApT[(size_t)row*HID + kb*8]);
  }
  __syncthreads();
  f32x4 acc[4] = {{0.f,0.f,0.f,0.f},{0.f,0.f,0.f,0.f},{0.f,0.f,0.f,0.f},{0.f,0.f,0.f,0.f}};
  #pragma unroll
  for (int i=0;i<8;i++){
    int cb = i & 1;
    if (i < 7){
      int kc = (i+1)*64;
      #pragma unroll
      for (int p=0;p<2;p++){
        int idx = tid + p*256;
        int row = idx >> 3, kb = idx & 7;
        *reinterpret_cast<short8v*>(&Hsh[cb^1][row][kb*8]) =
          *reinterpret_cast<const short8v*>(&hb[(size_t)(m0+row)*HID + kc + kb*8]);
        *reinterpret_cast<short8v*>(&Bsh[cb^1][row][kb*8]) =
          *reinterpret_cast<const short8v*>(&ApT[(size_t)row*HID + kc + kb*8]);
      }
    }
    short8v a0 = *reinterpret_cast<const short8v*>(&Hsh[cb][w*16 + c][q*8]);
    short8v a1 = *reinterpret_cast<const short8v*>(&Hsh[cb][w*16 + c][32 + q*8]);
    #pragma unroll
    for (int t=0;t<4;t++){
      short8v b0 = *reinterpret_cast<const short8v*>(&Bsh[cb][t*16 + c][q*8]);
      short8v b1 = *reinterpret_cast<const short8v*>(&Bsh[cb][t*16 + c][32 + q*8]);
      acc[t] = __builtin_amdgcn_mfma_f32_16x16x32_bf16(a0, b0, acc[t], 0, 0, 0);
      acc[t] = __builtin_amdgcn_mfma_f32_16x16x32_bf16(a1, b1, acc[t], 0, 0, 0);
    }
    __syncthreads();
  }
  (void)srow; (void)skb;
  #pragma unroll
  for (int t=0;t<4;t++){
    int s = t*16 + c;
    float ga = GA[s], ba = BA[s];
    #pragma unroll
    for (int r=0;r<4;r++){
      int m = m0 + w*16 + q*4 + r;
      U[(size_t)m*STATE + s] = (_Float16)fmaf(KTAN, rs[r]*(acc[t][r] - mu[r]*ga) + ba, KTAN);
    }
  }
}

// ---------------------------------------------------------------------------
// Chunked scan with contraction warmup (R12-verified), U in fp16.
__global__ __launch_bounds__(64) void k_scan(const _Float16* __restrict__ U,
                                             short* __restrict__ H)
{
  int b = blockIdx.x >> 5;
  int p = blockIdx.x & 31;
  int s = threadIdx.x;
  const _Float16* Ub = U + (size_t)b*SEQ*STATE + s;
  short* Hb = H + (size_t)b*SEQ*STATE + s;
  float r = 0.5f;
  float cur[32], nxt[32];
  int t = (p == 0) ? 0 : (p*64 - WARMUP);
  int nsub = (p == 0) ? 2 : 3;
  #pragma unroll
  for (int i=0;i<32;i++) cur[i] = (float)Ub[(t+i)*STATE];
  for (int cidx=0; cidx<nsub; ++cidx){
    bool has_next = (cidx+1 < nsub);
    if (has_next){
      #pragma unroll
      for (int i=0;i<32;i++) nxt[i] = (float)Ub[(t+32+i)*STATE];
    }
    if ((p == 0) || (cidx > 0)){
      #pragma unroll
      for (int i=0;i<32;i++){
        float e = fast_exp2(fmaf(-2.f*KTAN, r, cur[i]));
        r = fast_rcp(1.f + e);
        Hb[(t+i)*STATE] = f2bf(fmaf(-2.f, r, 1.f));
      }
    } else {
      #pragma unroll
      for (int i=0;i<32;i++){
        float e = fast_exp2(fmaf(-2.f*KTAN, r, cur[i]));
        r = fast_rcp(1.f + e);
      }
    }
    if (has_next){
      #pragma unroll
      for (int i=0;i<32;i++) cur[i] = nxt[i];
    }
    t += 32;
  }
}

// ---------------------------------------------------------------------------
// Y epilogue (R12-verified): MFMA -> Ysh(bf16 LDS) -> vectorized short8 h-RMW.
__global__ __launch_bounds__(256) void k_yep4(
    short* __restrict__ h, const short* __restrict__ Hg,
    const short* __restrict__ Cb, const float* __restrict__ Dl,
    const float* __restrict__ gl, const float* __restrict__ bl,
    const float2* __restrict__ stats_in, float2* __restrict__ stats_out)
{
  __shared__ __align__(16) short Hsh[64][72];   // 9.2 KB
  __shared__ __align__(16) short Csh[64][72];   // 9.2 KB
  __shared__ __align__(16) short Ysh[64][76];   // 9.7 KB
  int m0 = blockIdx.x * 64;
  int tid = threadIdx.x;
  int w = tid >> 6, lane = tid & 63;
  int c = lane & 15, q = lane >> 4;
  int vrow = tid >> 3;
  int vcb  = tid & 7;
  #pragma unroll
  for (int p=0;p<2;p++){
    int idx = tid + p*256;
    int row = idx >> 3, kb = idx & 7;
    *reinterpret_cast<short8v*>(&Hsh[row][kb*8]) =
      *reinterpret_cast<const short8v*>(&Hg[(size_t)(m0+row)*STATE + kb*8]);
  }
  float2 sin0 = stats_in[m0 + vrow];
  float2 sin1 = stats_in[m0 + 32 + vrow];
  float sum0=0.f, sq0=0.f, sum1=0.f, sq1=0.f;
  __syncthreads();
  short8v a0 = *reinterpret_cast<const short8v*>(&Hsh[w*16 + c][q*8]);
  short8v a1 = *reinterpret_cast<const short8v*>(&Hsh[w*16 + c][32 + q*8]);
  for (int jc=0; jc<HID; jc+=64){
    #pragma unroll
    for (int p=0;p<2;p++){
      int idx = tid + p*256;
      int col = idx >> 3, kb = idx & 7;
      *reinterpret_cast<short8v*>(&Csh[col][kb*8]) =
        *reinterpret_cast<const short8v*>(&Cb[(size_t)(jc+col)*STATE + kb*8]);
    }
    __syncthreads();
    #pragma unroll
    for (int t=0;t<4;t++){
      short8v b0 = *reinterpret_cast<const short8v*>(&Csh[t*16 + c][q*8]);
      short8v b1 = *reinterpret_cast<const short8v*>(&Csh[t*16 + c][32 + q*8]);
      f32x4 a = {0.f,0.f,0.f,0.f};
      a = __builtin_amdgcn_mfma_f32_16x16x32_bf16(a0, b0, a, 0, 0, 0);
      a = __builtin_amdgcn_mfma_f32_16x16x32_bf16(a1, b1, a, 0, 0, 0);
      #pragma unroll
      for (int r=0;r<4;r++)
        Ysh[w*16 + q*4 + r][t*16 + c] = f2bf(a[r]);
    }
    __syncthreads();
    int col0 = jc + vcb*8;
    float4 gA = CF4(&gl[col0]), gB = CF4(&gl[col0+4]);
    float4 bA = CF4(&bl[col0]), bB = CF4(&bl[col0+4]);
    float4 dA = CF4(&Dl[col0]), dB = CF4(&Dl[col0+4]);
    float ga[8] = {gA.x,gA.y,gA.z,gA.w,gB.x,gB.y,gB.z,gB.w};
    float ba[8] = {bA.x,bA.y,bA.z,bA.w,bB.x,bB.y,bB.z,bB.w};
    float da[8] = {dA.x,dA.y,dA.z,dA.w,dB.x,dB.y,dB.z,dB.w};
    #pragma unroll
    for (int rep=0; rep<2; ++rep){
      int row = vrow + rep*32;
      int m = m0 + row;
      float mu_ = rep ? sin1.x : sin0.x;
      float rs_ = rep ? sin1.y : sin0.y;
      short8v hv = *reinterpret_cast<const short8v*>(&h[(size_t)m*HID + col0]);
      short8v yv = *reinterpret_cast<const short8v*>(&Ysh[row][vcb*8]);
      short8v ov;
      float lsum=0.f, lsq=0.f;
      #pragma unroll
      for (int i=0;i<8;i++){
        float hvf = bf2f(hv[i]);
        float o = hvf + bf2f(yv[i]) + fmaf((hvf-mu_)*rs_, ga[i], ba[i])*da[i];
        ov[i] = f2bf(o);
        lsum += o; lsq += o*o;
      }
      *reinterpret_cast<short8v*>(&h[(size_t)m*HID + col0]) = ov;
      if (rep) { sum1 += lsum; sq1 += lsq; } else { sum0 += lsum; sq0 += lsq; }
    }
  }
  #pragma unroll
  for (int off=1; off<8; off<<=1){
    sum0 += __shfl_xor(sum0, off);  sq0 += __shfl_xor(sq0, off);
    sum1 += __shfl_xor(sum1, off);  sq1 += __shfl_xor(sq1, off);
  }
  if (vcb == 0){
    float m0v = sum0*(1.f/HID);
    float v0 = sq0*(1.f/HID) - m0v*m0v;
    stats_out[m0 + vrow] = make_float2(m0v, rsqrtf(fmaxf(v0,0.f)+EPS));
    float m1v = sum1*(1.f/HID);
    float v1 = sq1*(1.f/HID) - m1v*m1v;
    stats_out[m0 + 32 + vrow] = make_float2(m1v, rsqrtf(fmaxf(v1,0.f)+EPS));
  }
}

// ---------------------------------------------------------------------------
__global__ __launch_bounds__(256) void k_head(const short* __restrict__ h,
   const float2* __restrict__ stats, const float* __restrict__ ng, const float* __restrict__ nb,
   const float* __restrict__ W1, const float* __restrict__ b1,
   const float* __restrict__ W2, const float* __restrict__ b2,
   float* __restrict__ out)
{
  int bb = blockIdx.x;
  int m = bb*SEQ + (SEQ-1);
  int tid = threadIdx.x;
  __shared__ float xs[HID];
  __shared__ float red[8];
  float2 st = stats[m];
  #pragma unroll
  for (int i=0;i<2;i++){
    int j = tid + i*256;
    float v = bf2f(h[(size_t)m*HID + j]);
    xs[j] = fmaf((v - st.x)*st.y, ng[j], nb[j]);
  }
  __syncthreads();
  float acc = b1[tid];
  #pragma unroll 8
  for (int j=0;j<HID;j++) acc = fmaf(xs[j], W1[j*(HID/2) + tid], acc);
  float ge = 0.5f*acc*(1.f + erff(acc*0.70710678118654752f));
  float p0 = ge*W2[tid*2+0];
  float p1 = ge*W2[tid*2+1];
  #pragma unroll
  for (int off=32; off; off>>=1){ p0 += __shfl_down(p0, off); p1 += __shfl_down(p1, off); }
  int wid = tid>>6;
  if ((tid&63)==0){ red[wid*2]=p0; red[wid*2+1]=p1; }
  __syncthreads();
  if (tid==0){
    float o0=b2[0], o1=b2[1];
    #pragma unroll
    for (int w=0;w<4;w++){ o0+=red[w*2]; o1+=red[w*2+1]; }
    out[bb*2+0]=o0; out[bb*2+1]=o1;
  }
}

// ---------------------------------------------------------------------------
extern "C" void kernel_launch(void* const* d_in, const int* in_sizes, int n_in,
                              void* d_out, int out_size, void* d_ws, size_t ws_size,
                              hipStream_t stream)
{
  (void)in_sizes; (void)n_in; (void)out_size; (void)ws_size;
  const float* x   = (const float*)d_in[0];
  const float* Win = (const float*)d_in[1];
  const float* bin = (const float*)d_in[2];
  const float* A   = (const float*)d_in[3];
  const float* C   = (const float*)d_in[4];
  const float* Dv  = (const float*)d_in[5];
  const float* lng = (const float*)d_in[6];
  const float* lnb = (const float*)d_in[7];
  const float* ng  = (const float*)d_in[8];
  const float* nb  = (const float*)d_in[9];
  const float* W1  = (const float*)d_in[10];
  const float* b1  = (const float*)d_in[11];
  const float* W2  = (const float*)d_in[12];
  const float* b2  = (const float*)d_in[13];
  float* out = (float*)d_out;
  char* ws = (char*)d_ws;
  short*     hb   = (short*)(ws + 0);                    //  67,108,864 (bf16)
  _Float16*  Ubuf = (_Float16*)(ws + (size_t)67108864);  //   8,388,608 (fp16)
  short*     Hbuf = (short*)(ws + (size_t)83886080);     //   8,388,608 (bf16)
  float2*    st0  = (float2*)(ws + (size_t)92274688);    //     524,288
  float2*    st1  = (float2*)(ws + (size_t)92798976);    //     524,288
  short*     ApT  = (short*)(ws + (size_t)93323264);     //     262,144 (bf16)
  float*     GAb  = (float*)(ws + (size_t)93585408);     //       1,024
  float*     BAb  = (float*)(ws + (size_t)93586432);     //       1,024
  float*     binAb= (float*)(ws + (size_t)93587456);     //         256
  short*     Cb   = (short*)(ws + (size_t)93587712);     //     262,144 (bf16)
  short*     WinT = (short*)(ws + (size_t)93849856);     //      32,768 (bf16)
  short*     WA1Th= (short*)(ws + (size_t)93882624);     //       4,096 (bf16)
  short*     WA1Tl= (short*)(ws + (size_t)93886720);     //       4,096 (bf16)

  hipLaunchKernelGGL(k_prep,  dim3(38), dim3(256), 0, stream,
      A, lng, lnb, Win, bin, C, ApT, GAb, BAb, WA1Th, WA1Tl, binAb, Cb, WinT);
  hipLaunchKernelGGL(k_input, dim3(NTOK/64), dim3(256), 0, stream,
      x, WinT, bin, WA1Th, WA1Tl, binAb, GAb, BAb, hb, Ubuf, st0);
  float2* scur = st0; float2* snxt = st1;
  for (int l=0; l<NLAYERS; ++l){
    if (l > 0){
      hipLaunchKernelGGL(k_ugemm, dim3(NTOK/64), dim3(256), 0, stream,
          hb, scur, ApT + l*HID*STATE, GAb + l*STATE, BAb + l*STATE, Ubuf);
    }
    hipLaunchKernelGGL(k_scan, dim3(BATCH*NCHUNK), dim3(64), 0, stream, Ubuf, Hbuf);
    hipLaunchKernelGGL(k_yep4, dim3(NTOK/64), dim3(256), 0, stream,
        hb, Hbuf, Cb + l*HID*STATE, Dv + l*HID, lng + l*HID, lnb + l*HID, scur, snxt);
    float2* t = scur; scur = snxt; snxt = t;
  }
  hipLaunchKernelGGL(k_head, dim3(BATCH), dim3(256), 0, stream,
      hb, scur, ng, nb, W1, b1, W2, b2, out);
}

// Round 19
// 243.906 us; speedup vs baseline: 1.3042x; 1.0071x over previous
//
#include <hip/hip_runtime.h>

#define BATCH   32
#define SEQ     2048
#define IN_DIM  32
#define HID     512
#define STATE   64
#define NLAYERS 4
#define NTOK    (BATCH*SEQ)          // 65536
#define EPS     1e-5f
#define KTAN    2.8853900817779268f  // 2*log2(e)
#define NCHUNK  64                   // scan chunks per batch (32 outputs each)
#define WARMUP  32                   // contraction warmup steps

#define CF4(p) (*reinterpret_cast<const float4*>(p))

typedef __attribute__((ext_vector_type(8))) short short8v;
typedef __attribute__((ext_vector_type(4))) float f32x4;

__device__ __forceinline__ float fast_exp2(float x){ return __builtin_amdgcn_exp2f(x); }
__device__ __forceinline__ float fast_rcp(float x){ return __builtin_amdgcn_rcpf(x); }
__device__ __forceinline__ short f2bf(float f){           // RNE float->bf16
  unsigned u = __float_as_uint(f);
  unsigned r = (u + 0x7FFF + ((u>>16)&1)) >> 16;
  return (short)r;
}
__device__ __forceinline__ float bf2f(short s){
  return __uint_as_float(((unsigned)(unsigned short)s) << 16);
}

// ---------------------------------------------------------------------------
// All precompute, 38 blocks x 256 threads.
__global__ __launch_bounds__(256) void k_prep(
    const float* __restrict__ A, const float* __restrict__ g,
    const float* __restrict__ b, const float* __restrict__ Win,
    const float* __restrict__ bin, const float* __restrict__ C,
    short* __restrict__ ApT, float* __restrict__ GA, float* __restrict__ BA,
    short* __restrict__ WA1Th, short* __restrict__ WA1Tl,
    float* __restrict__ binA, short* __restrict__ Cb, short* __restrict__ WinT)
{
  __shared__ float red[4][64], red2[4][64];
  int tid = threadIdx.x;
  int s = tid & 63, part = tid >> 6;
  int blk = blockIdx.x;
  if (blk < NLAYERS){
    int l = blk;
    const float* Al = A + l*HID*STATE;
    const float* Cl = C + l*HID*STATE;
    const float* gl = g + l*HID;
    const float* bl = b + l*HID;
    float ga=0.f, ba=0.f;
    for (int j=part*128; j<(part+1)*128; ++j){
      float a  = Al[j*STATE+s];
      float ap = gl[j]*a;
      ApT[l*HID*STATE + s*HID + j] = f2bf(ap);
      Cb[l*HID*STATE + j*STATE + s] = f2bf(Cl[j*STATE+s]);
      ga += ap; ba = fmaf(bl[j], a, ba);
    }
    red[part][s]=ga; red2[part][s]=ba;
    __syncthreads();
    if (tid < 64){
      GA[l*STATE+s] = red[0][s]+red[1][s]+red[2][s]+red[3][s];
      BA[l*STATE+s] = red2[0][s]+red2[1][s]+red2[2][s]+red2[3][s];
    }
  } else if (blk < NLAYERS+32){
    int k = blk - NLAYERS;
    const float* w = Win + k*HID;
    float acc = 0.f;
    for (int j=part*128; j<(part+1)*128; ++j)
      acc = fmaf(w[j], g[j]*A[j*STATE+s], acc);
    red[part][s] = acc;
    __syncthreads();
    if (tid < 64){
      float v = red[0][s]+red[1][s]+red[2][s]+red[3][s];
      short hi = f2bf(v);
      WA1Th[s*IN_DIM + k] = hi;
      WA1Tl[s*IN_DIM + k] = f2bf(v - bf2f(hi));
    }
  } else if (blk == NLAYERS+32){
    float acc = 0.f;
    for (int j=part*128; j<(part+1)*128; ++j)
      acc = fmaf(bin[j], g[j]*A[j*STATE+s], acc);
    red[part][s] = acc;
    __syncthreads();
    if (tid < 64) binA[s] = red[0][s]+red[1][s]+red[2][s]+red[3][s];
  } else {
    for (int e = tid; e < HID*IN_DIM; e += 256){
      int cc = e >> 5, k = e & 31;
      WinT[cc*IN_DIM + k] = f2bf(Win[k*HID + cc]);
    }
  }
}

// ---------------------------------------------------------------------------
// Fused input via MFMA: h(bf16)=x@Win+bin, stats0, U0 (3-term split, fp16).
// Ysh double-buffered: one barrier per 64-col chunk.
__global__ __launch_bounds__(256) void k_input(const float* __restrict__ x,
    const short* __restrict__ WinT, const float* __restrict__ bin,
    const short* __restrict__ WA1Th, const short* __restrict__ WA1Tl,
    const float* __restrict__ binA,
    const float* __restrict__ GA0, const float* __restrict__ BA0,
    short* __restrict__ h, _Float16* __restrict__ U, float2* __restrict__ stats)
{
  __shared__ __align__(16) short xhi[64][72];
  __shared__ __align__(16) short xlo[64][72];
  __shared__ __align__(16) short Ysh[2][64][76];
  __shared__ float2 statS[64];
  int m0 = blockIdx.x * 64;
  int tid = threadIdx.x;
  int w = tid >> 6, lane = tid & 63;
  int c = lane & 15, q = lane >> 4;
  int vrow = tid >> 3, vcb = tid & 7;   // vector phase: 32 rows x 8 colblocks
  #pragma unroll
  for (int i=0;i<8;i++){
    int idx = tid + i*256;
    int row = idx >> 5, k = idx & 31;
    float v = x[(size_t)(m0+row)*IN_DIM + k];
    short hi = f2bf(v);
    xhi[row][k] = hi;
    xlo[row][k] = f2bf(v - bf2f(hi));
  }
  __syncthreads();
  short8v ah = *reinterpret_cast<const short8v*>(&xhi[w*16 + c][q*8]);
  short8v al = *reinterpret_cast<const short8v*>(&xlo[w*16 + c][q*8]);
  float sum0=0.f, sq0=0.f, sum1=0.f, sq1=0.f;
  for (int jc=0; jc<HID; jc+=64){
    int cb = (jc >> 6) & 1;
    #pragma unroll
    for (int t=0;t<4;t++){
      short8v bv = *reinterpret_cast<const short8v*>(&WinT[(size_t)(jc + t*16 + c)*IN_DIM + q*8]);
      f32x4 a = {0.f,0.f,0.f,0.f};
      a = __builtin_amdgcn_mfma_f32_16x16x32_bf16(ah, bv, a, 0, 0, 0);
      int col = jc + t*16 + c;
      float bj = bin[col];
      #pragma unroll
      for (int r=0;r<4;r++)
        Ysh[cb][w*16 + q*4 + r][t*16 + c] = f2bf(a[r] + bj);
    }
    __syncthreads();
    #pragma unroll
    for (int rep=0; rep<2; ++rep){
      int row = vrow + rep*32;
      int m = m0 + row;
      short8v yv = *reinterpret_cast<const short8v*>(&Ysh[cb][row][vcb*8]);
      *reinterpret_cast<short8v*>(&h[(size_t)m*HID + jc + vcb*8]) = yv;
      float lsum=0.f, lsq=0.f;
      #pragma unroll
      for (int i=0;i<8;i++){
        float o = bf2f(yv[i]);
        lsum += o; lsq += o*o;
      }
      if (rep) { sum1 += lsum; sq1 += lsq; } else { sum0 += lsum; sq0 += lsq; }
    }
  }
  #pragma unroll
  for (int off=1; off<8; off<<=1){
    sum0 += __shfl_xor(sum0, off);  sq0 += __shfl_xor(sq0, off);
    sum1 += __shfl_xor(sum1, off);  sq1 += __shfl_xor(sq1, off);
  }
  if (vcb == 0){
    float m0v = sum0*(1.f/HID);
    float v0 = sq0*(1.f/HID) - m0v*m0v;
    float2 s0 = make_float2(m0v, rsqrtf(fmaxf(v0,0.f)+EPS));
    stats[m0 + vrow] = s0;  statS[vrow] = s0;
    float m1v = sum1*(1.f/HID);
    float v1 = sq1*(1.f/HID) - m1v*m1v;
    float2 s1 = make_float2(m1v, rsqrtf(fmaxf(v1,0.f)+EPS));
    stats[m0 + 32 + vrow] = s1;  statS[32 + vrow] = s1;
  }
  __syncthreads();
  float mu[4], rs[4];
  #pragma unroll
  for (int r=0;r<4;r++){
    float2 s2 = statS[w*16 + q*4 + r];
    mu[r]=s2.x; rs[r]=s2.y;
  }
  #pragma unroll
  for (int t=0;t<4;t++){
    short8v bh  = *reinterpret_cast<const short8v*>(&WA1Th[(size_t)(t*16 + c)*IN_DIM + q*8]);
    short8v blv = *reinterpret_cast<const short8v*>(&WA1Tl[(size_t)(t*16 + c)*IN_DIM + q*8]);
    f32x4 a = {0.f,0.f,0.f,0.f};
    a = __builtin_amdgcn_mfma_f32_16x16x32_bf16(ah, bh, a, 0, 0, 0);
    a = __builtin_amdgcn_mfma_f32_16x16x32_bf16(al, bh, a, 0, 0, 0);
    a = __builtin_amdgcn_mfma_f32_16x16x32_bf16(ah, blv, a, 0, 0, 0);
    int s = t*16 + c;
    float ga = GA0[s], ba = BA0[s], bA = binA[s];
    #pragma unroll
    for (int r=0;r<4;r++){
      int m = m0 + w*16 + q*4 + r;
      float u = a[r] + bA;
      U[(size_t)m*STATE + s] = (_Float16)fmaf(KTAN, rs[r]*(u - mu[r]*ga) + ba, KTAN);
    }
  }
}

// ---------------------------------------------------------------------------
// U = KTAN*( rstd*(h@A' - mu*GA) + BA ) + KTAN via bf16 MFMA (layers 1..3).
// Double-buffered LDS; one barrier per K-chunk; fp16 U out. (R18-verified)
__global__ __launch_bounds__(256) void k_ugemm(const short* __restrict__ hb,
    const float2* __restrict__ stats, const short* __restrict__ ApT,
    const float* __restrict__ GA, const float* __restrict__ BA,
    _Float16* __restrict__ U)
{
  __shared__ __align__(16) short Hsh[2][64][72];   // 18.4 KB
  __shared__ __align__(16) short Bsh[2][64][72];   // 18.4 KB
  int m0 = blockIdx.x * 64;
  int tid = threadIdx.x;
  int w = tid >> 6, lane = tid & 63;
  int c = lane & 15, q = lane >> 4;
  float mu[4], rs[4];
  #pragma unroll
  for (int r=0;r<4;r++){
    float2 s2 = stats[m0 + w*16 + q*4 + r];
    mu[r]=s2.x; rs[r]=s2.y;
  }
  #pragma unroll
  for (int p=0;p<2;p++){
    int idx = tid + p*256;
    int row = idx >> 3, kb = idx & 7;
    *reinterpret_cast<short8v*>(&Hsh[0][row][kb*8]) =
      *reinterpret_cast<const short8v*>(&hb[(size_t)(m0+row)*HID + kb*8]);
    *reinterpret_cast<short8v*>(&Bsh[0][row][kb*8]) =
      *reinterpret_cast<const short8v*>(&ApT[(size_t)row*HID + kb*8]);
  }
  __syncthreads();
  f32x4 acc[4] = {{0.f,0.f,0.f,0.f},{0.f,0.f,0.f,0.f},{0.f,0.f,0.f,0.f},{0.f,0.f,0.f,0.f}};
  #pragma unroll
  for (int i=0;i<8;i++){
    int cb = i & 1;
    if (i < 7){
      int kc = (i+1)*64;
      #pragma unroll
      for (int p=0;p<2;p++){
        int idx = tid + p*256;
        int row = idx >> 3, kb = idx & 7;
        *reinterpret_cast<short8v*>(&Hsh[cb^1][row][kb*8]) =
          *reinterpret_cast<const short8v*>(&hb[(size_t)(m0+row)*HID + kc + kb*8]);
        *reinterpret_cast<short8v*>(&Bsh[cb^1][row][kb*8]) =
          *reinterpret_cast<const short8v*>(&ApT[(size_t)row*HID + kc + kb*8]);
      }
    }
    short8v a0 = *reinterpret_cast<const short8v*>(&Hsh[cb][w*16 + c][q*8]);
    short8v a1 = *reinterpret_cast<const short8v*>(&Hsh[cb][w*16 + c][32 + q*8]);
    #pragma unroll
    for (int t=0;t<4;t++){
      short8v b0 = *reinterpret_cast<const short8v*>(&Bsh[cb][t*16 + c][q*8]);
      short8v b1 = *reinterpret_cast<const short8v*>(&Bsh[cb][t*16 + c][32 + q*8]);
      acc[t] = __builtin_amdgcn_mfma_f32_16x16x32_bf16(a0, b0, acc[t], 0, 0, 0);
      acc[t] = __builtin_amdgcn_mfma_f32_16x16x32_bf16(a1, b1, acc[t], 0, 0, 0);
    }
    __syncthreads();
  }
  #pragma unroll
  for (int t=0;t<4;t++){
    int s = t*16 + c;
    float ga = GA[s], ba = BA[s];
    #pragma unroll
    for (int r=0;r<4;r++){
      int m = m0 + w*16 + q*4 + r;
      U[(size_t)m*STATE + s] = (_Float16)fmaf(KTAN, rs[r]*(acc[t][r] - mu[r]*ga) + ba, KTAN);
    }
  }
}

// ---------------------------------------------------------------------------
// Chunked scan, 32-output chunks + 32-step warmup (warmup length unchanged
// from the verified version -> identical truncation error). grid = BATCH*64.
__global__ __launch_bounds__(64) void k_scan(const _Float16* __restrict__ U,
                                             short* __restrict__ H)
{
  int b = blockIdx.x >> 6;           // NCHUNK=64 chunks per batch
  int p = blockIdx.x & 63;
  int s = threadIdx.x;
  const _Float16* Ub = U + (size_t)b*SEQ*STATE + s;
  short* Hb = H + (size_t)b*SEQ*STATE + s;
  float r = 0.5f;
  float cur[32], nxt[32];
  int t = (p == 0) ? 0 : (p*32 - WARMUP);
  int nsub = (p == 0) ? 1 : 2;
  #pragma unroll
  for (int i=0;i<32;i++) cur[i] = (float)Ub[(t+i)*STATE];
  for (int cidx=0; cidx<nsub; ++cidx){
    bool has_next = (cidx+1 < nsub);
    if (has_next){
      #pragma unroll
      for (int i=0;i<32;i++) nxt[i] = (float)Ub[(t+32+i)*STATE];
    }
    if ((p == 0) || (cidx > 0)){
      #pragma unroll
      for (int i=0;i<32;i++){
        float e = fast_exp2(fmaf(-2.f*KTAN, r, cur[i]));
        r = fast_rcp(1.f + e);
        Hb[(t+i)*STATE] = f2bf(fmaf(-2.f, r, 1.f));
      }
    } else {
      #pragma unroll
      for (int i=0;i<32;i++){
        float e = fast_exp2(fmaf(-2.f*KTAN, r, cur[i]));
        r = fast_rcp(1.f + e);
      }
    }
    if (has_next){
      #pragma unroll
      for (int i=0;i<32;i++) cur[i] = nxt[i];
    }
    t += 32;
  }
}

// ---------------------------------------------------------------------------
// Y epilogue (R12-verified): MFMA -> Ysh(bf16 LDS) -> vectorized short8 h-RMW.
__global__ __launch_bounds__(256) void k_yep4(
    short* __restrict__ h, const short* __restrict__ Hg,
    const short* __restrict__ Cb, const float* __restrict__ Dl,
    const float* __restrict__ gl, const float* __restrict__ bl,
    const float2* __restrict__ stats_in, float2* __restrict__ stats_out)
{
  __shared__ __align__(16) short Hsh[64][72];   // 9.2 KB
  __shared__ __align__(16) short Csh[64][72];   // 9.2 KB
  __shared__ __align__(16) short Ysh[64][76];   // 9.7 KB
  int m0 = blockIdx.x * 64;
  int tid = threadIdx.x;
  int w = tid >> 6, lane = tid & 63;
  int c = lane & 15, q = lane >> 4;
  int vrow = tid >> 3;
  int vcb  = tid & 7;
  #pragma unroll
  for (int p=0;p<2;p++){
    int idx = tid + p*256;
    int row = idx >> 3, kb = idx & 7;
    *reinterpret_cast<short8v*>(&Hsh[row][kb*8]) =
      *reinterpret_cast<const short8v*>(&Hg[(size_t)(m0+row)*STATE + kb*8]);
  }
  float2 sin0 = stats_in[m0 + vrow];
  float2 sin1 = stats_in[m0 + 32 + vrow];
  float sum0=0.f, sq0=0.f, sum1=0.f, sq1=0.f;
  __syncthreads();
  short8v a0 = *reinterpret_cast<const short8v*>(&Hsh[w*16 + c][q*8]);
  short8v a1 = *reinterpret_cast<const short8v*>(&Hsh[w*16 + c][32 + q*8]);
  for (int jc=0; jc<HID; jc+=64){
    #pragma unroll
    for (int p=0;p<2;p++){
      int idx = tid + p*256;
      int col = idx >> 3, kb = idx & 7;
      *reinterpret_cast<short8v*>(&Csh[col][kb*8]) =
        *reinterpret_cast<const short8v*>(&Cb[(size_t)(jc+col)*STATE + kb*8]);
    }
    __syncthreads();
    #pragma unroll
    for (int t=0;t<4;t++){
      short8v b0 = *reinterpret_cast<const short8v*>(&Csh[t*16 + c][q*8]);
      short8v b1 = *reinterpret_cast<const short8v*>(&Csh[t*16 + c][32 + q*8]);
      f32x4 a = {0.f,0.f,0.f,0.f};
      a = __builtin_amdgcn_mfma_f32_16x16x32_bf16(a0, b0, a, 0, 0, 0);
      a = __builtin_amdgcn_mfma_f32_16x16x32_bf16(a1, b1, a, 0, 0, 0);
      #pragma unroll
      for (int r=0;r<4;r++)
        Ysh[w*16 + q*4 + r][t*16 + c] = f2bf(a[r]);
    }
    __syncthreads();
    int col0 = jc + vcb*8;
    float4 gA = CF4(&gl[col0]), gB = CF4(&gl[col0+4]);
    float4 bA = CF4(&bl[col0]), bB = CF4(&bl[col0+4]);
    float4 dA = CF4(&Dl[col0]), dB = CF4(&Dl[col0+4]);
    float ga[8] = {gA.x,gA.y,gA.z,gA.w,gB.x,gB.y,gB.z,gB.w};
    float ba[8] = {bA.x,bA.y,bA.z,bA.w,bB.x,bB.y,bB.z,bB.w};
    float da[8] = {dA.x,dA.y,dA.z,dA.w,dB.x,dB.y,dB.z,dB.w};
    #pragma unroll
    for (int rep=0; rep<2; ++rep){
      int row = vrow + rep*32;
      int m = m0 + row;
      float mu_ = rep ? sin1.x : sin0.x;
      float rs_ = rep ? sin1.y : sin0.y;
      short8v hv = *reinterpret_cast<const short8v*>(&h[(size_t)m*HID + col0]);
      short8v yv = *reinterpret_cast<const short8v*>(&Ysh[row][vcb*8]);
      short8v ov;
      float lsum=0.f, lsq=0.f;
      #pragma unroll
      for (int i=0;i<8;i++){
        float hvf = bf2f(hv[i]);
        float o = hvf + bf2f(yv[i]) + fmaf((hvf-mu_)*rs_, ga[i], ba[i])*da[i];
        ov[i] = f2bf(o);
        lsum += o; lsq += o*o;
      }
      *reinterpret_cast<short8v*>(&h[(size_t)m*HID + col0]) = ov;
      if (rep) { sum1 += lsum; sq1 += lsq; } else { sum0 += lsum; sq0 += lsq; }
    }
  }
  #pragma unroll
  for (int off=1; off<8; off<<=1){
    sum0 += __shfl_xor(sum0, off);  sq0 += __shfl_xor(sq0, off);
    sum1 += __shfl_xor(sum1, off);  sq1 += __shfl_xor(sq1, off);
  }
  if (vcb == 0){
    float m0v = sum0*(1.f/HID);
    float v0 = sq0*(1.f/HID) - m0v*m0v;
    stats_out[m0 + vrow] = make_float2(m0v, rsqrtf(fmaxf(v0,0.f)+EPS));
    float m1v = sum1*(1.f/HID);
    float v1 = sq1*(1.f/HID) - m1v*m1v;
    stats_out[m0 + 32 + vrow] = make_float2(m1v, rsqrtf(fmaxf(v1,0.f)+EPS));
  }
}

// ---------------------------------------------------------------------------
__global__ __launch_bounds__(256) void k_head(const short* __restrict__ h,
   const float2* __restrict__ stats, const float* __restrict__ ng, const float* __restrict__ nb,
   const float* __restrict__ W1, const float* __restrict__ b1,
   const float* __restrict__ W2, const float* __restrict__ b2,
   float* __restrict__ out)
{
  int bb = blockIdx.x;
  int m = bb*SEQ + (SEQ-1);
  int tid = threadIdx.x;
  __shared__ float xs[HID];
  __shared__ float red[8];
  float2 st = stats[m];
  #pragma unroll
  for (int i=0;i<2;i++){
    int j = tid + i*256;
    float v = bf2f(h[(size_t)m*HID + j]);
    xs[j] = fmaf((v - st.x)*st.y, ng[j], nb[j]);
  }
  __syncthreads();
  float acc = b1[tid];
  #pragma unroll 8
  for (int j=0;j<HID;j++) acc = fmaf(xs[j], W1[j*(HID/2) + tid], acc);
  float ge = 0.5f*acc*(1.f + erff(acc*0.70710678118654752f));
  float p0 = ge*W2[tid*2+0];
  float p1 = ge*W2[tid*2+1];
  #pragma unroll
  for (int off=32; off; off>>=1){ p0 += __shfl_down(p0, off); p1 += __shfl_down(p1, off); }
  int wid = tid>>6;
  if ((tid&63)==0){ red[wid*2]=p0; red[wid*2+1]=p1; }
  __syncthreads();
  if (tid==0){
    float o0=b2[0], o1=b2[1];
    #pragma unroll
    for (int w=0;w<4;w++){ o0+=red[w*2]; o1+=red[w*2+1]; }
    out[bb*2+0]=o0; out[bb*2+1]=o1;
  }
}

// ---------------------------------------------------------------------------
extern "C" void kernel_launch(void* const* d_in, const int* in_sizes, int n_in,
                              void* d_out, int out_size, void* d_ws, size_t ws_size,
                              hipStream_t stream)
{
  (void)in_sizes; (void)n_in; (void)out_size; (void)ws_size;
  const float* x   = (const float*)d_in[0];
  const float* Win = (const float*)d_in[1];
  const float* bin = (const float*)d_in[2];
  const float* A   = (const float*)d_in[3];
  const float* C   = (const float*)d_in[4];
  const float* Dv  = (const float*)d_in[5];
  const float* lng = (const float*)d_in[6];
  const float* lnb = (const float*)d_in[7];
  const float* ng  = (const float*)d_in[8];
  const float* nb  = (const float*)d_in[9];
  const float* W1  = (const float*)d_in[10];
  const float* b1  = (const float*)d_in[11];
  const float* W2  = (const float*)d_in[12];
  const float* b2  = (const float*)d_in[13];
  float* out = (float*)d_out;
  char* ws = (char*)d_ws;
  short*     hb   = (short*)(ws + 0);                    //  67,108,864 (bf16)
  _Float16*  Ubuf = (_Float16*)(ws + (size_t)67108864);  //   8,388,608 (fp16)
  short*     Hbuf = (short*)(ws + (size_t)83886080);     //   8,388,608 (bf16)
  float2*    st0  = (float2*)(ws + (size_t)92274688);    //     524,288
  float2*    st1  = (float2*)(ws + (size_t)92798976);    //     524,288
  short*     ApT  = (short*)(ws + (size_t)93323264);     //     262,144 (bf16)
  float*     GAb  = (float*)(ws + (size_t)93585408);     //       1,024
  float*     BAb  = (float*)(ws + (size_t)93586432);     //       1,024
  float*     binAb= (float*)(ws + (size_t)93587456);     //         256
  short*     Cb   = (short*)(ws + (size_t)93587712);     //     262,144 (bf16)
  short*     WinT = (short*)(ws + (size_t)93849856);     //      32,768 (bf16)
  short*     WA1Th= (short*)(ws + (size_t)93882624);     //       4,096 (bf16)
  short*     WA1Tl= (short*)(ws + (size_t)93886720);     //       4,096 (bf16)

  hipLaunchKernelGGL(k_prep,  dim3(38), dim3(256), 0, stream,
      A, lng, lnb, Win, bin, C, ApT, GAb, BAb, WA1Th, WA1Tl, binAb, Cb, WinT);
  hipLaunchKernelGGL(k_input, dim3(NTOK/64), dim3(256), 0, stream,
      x, WinT, bin, WA1Th, WA1Tl, binAb, GAb, BAb, hb, Ubuf, st0);
  float2* scur = st0; float2* snxt = st1;
  for (int l=0; l<NLAYERS; ++l){
    if (l > 0){
      hipLaunchKernelGGL(k_ugemm, dim3(NTOK/64), dim3(256), 0, stream,
          hb, scur, ApT + l*HID*STATE, GAb + l*STATE, BAb + l*STATE, Ubuf);
    }
    hipLaunchKernelGGL(k_scan, dim3(BATCH*NCHUNK), dim3(64), 0, stream, Ubuf, Hbuf);
    hipLaunchKernelGGL(k_yep4, dim3(NTOK/64), dim3(256), 0, stream,
        hb, Hbuf, Cb + l*HID*STATE, Dv + l*HID, lng + l*HID, lnb + l*HID, scur, snxt);
    float2* t = scur; scur = snxt; snxt = t;
  }
  hipLaunchKernelGGL(k_head, dim3(BATCH), dim3(256), 0, stream,
      hb, scur, ng, nb, W1, b1, W2, b2, out);
}